// Round 5
// baseline (343.596 us; speedup 1.0000x reference)
//
#include <hip/hip_runtime.h>
#include <stdint.h>

#define NTOK 1024
#define NH 12
#define QPSLAB 2801664   // 1024*2736
#define SLA 933888       // 1024*912 (f32 elems per acc slab)

typedef short bf16x8 __attribute__((ext_vector_type(8)));
typedef float f32x4 __attribute__((ext_vector_type(4)));
typedef uint32_t u32x4 __attribute__((ext_vector_type(4)));

__device__ __forceinline__ unsigned short f2bf(float f) {
  union { float f; uint32_t u; } x; x.f = f;
  uint32_t r = x.u + 0x7FFFu + ((x.u >> 16) & 1u);
  return (unsigned short)(r >> 16);
}
__device__ __forceinline__ float bf2f(unsigned short u) {
  union { uint32_t u; float f; } x; x.u = ((uint32_t)u) << 16;
  return x.f;
}
__device__ __forceinline__ bf16x8 pack8(float4 a, float4 b) {
  bf16x8 r;
  r[0] = (short)f2bf(a.x); r[1] = (short)f2bf(a.y);
  r[2] = (short)f2bf(a.z); r[3] = (short)f2bf(a.w);
  r[4] = (short)f2bf(b.x); r[5] = (short)f2bf(b.y);
  r[6] = (short)f2bf(b.z); r[7] = (short)f2bf(b.w);
  return r;
}
// sum 4 f32 slabs (stride SLA) of 8 consecutive elems -> bf16x8
__device__ __forceinline__ bf16x8 sum4pack(const float* __restrict__ p) {
  float4 s0 = *(const float4*)(p);
  float4 s1 = *(const float4*)(p + 4);
#pragma unroll
  for (int z = 1; z < 4; ++z) {
    const float* q = p + (size_t)z * SLA;
    float4 a = *(const float4*)(q), b = *(const float4*)(q + 4);
    s0.x += a.x; s0.y += a.y; s0.z += a.z; s0.w += a.w;
    s1.x += b.x; s1.y += b.y; s1.z += b.z; s1.w += b.w;
  }
  return pack8(s0, s1);
}

// ---------------------------------------------------------------------------
// prep: LDS-tiled transposes (coalesced both sides) + vectorized copies.
// ---------------------------------------------------------------------------
__global__ __launch_bounds__(256) void prep_k(
    const float* __restrict__ single, const float* __restrict__ Wq,
    const float* __restrict__ Wk, const float* __restrict__ Wv,
    const float* __restrict__ Wqp, const float* __restrict__ Wkp,
    const float* __restrict__ Wvp, const float* __restrict__ Wpo,
    const float* __restrict__ Wo, const float* __restrict__ Wpb,
    const float* __restrict__ bq, const float* __restrict__ bk,
    const float* __restrict__ bv, const float* __restrict__ bqp,
    const float* __restrict__ bkp, const float* __restrict__ bvp,
    unsigned short* __restrict__ sgl, unsigned short* __restrict__ wcat,
    unsigned short* __restrict__ WB, unsigned short* __restrict__ wpoA,
    float* __restrict__ bcat, unsigned short* __restrict__ wpbt)
{
  const int bid = blockIdx.x, t = threadIdx.x;
  if (bid < 2628) {
    __shared__ unsigned short tl[16][72];
    int b = bid;
    const float* src; unsigned short* dst; int N, dstld, rowbase;
    if (b < 1728) {
      int j = b / 576; b -= j * 576;
      src = (j == 0) ? Wq : (j == 1) ? Wk : Wv;
      N = 768; dst = wcat; dstld = 768; rowbase = j * 768;
    } else if (b < 2052) {
      b -= 1728; int j = b / 108; b -= j * 108;
      src = (j == 0) ? Wqp : (j == 1) ? Wkp : Wvp;
      N = 144; dst = wcat; dstld = 768; rowbase = 2304 + j * 144;
    } else {
      b -= 2052; src = Wo; N = 768; dst = WB; dstld = 912; rowbase = 0;
    }
    const int k0 = (b % 12) * 64, n0 = (b / 12) * 16;
#pragma unroll
    for (int i = 0; i < 4; ++i) {
      int kk = (t >> 4) + i * 16;
      int nn = t & 15;
      tl[nn][kk] = f2bf(src[(size_t)(k0 + kk) * N + n0 + nn]);
    }
    __syncthreads();
#pragma unroll
    for (int i = 0; i < 4; ++i) {
      int kk = t & 63;
      int nn = (t >> 6) + i * 4;
      dst[(size_t)(rowbase + n0 + nn) * dstld + k0 + kk] = tl[nn][kk];
    }
    return;
  }
  if (bid < 3396) {           // sgl float4 copy
    int i = (bid - 2628) * 256 + t;
    float4 v = *(const float4*)(single + (size_t)i * 4);
    ushort4 o;
    o.x = f2bf(v.x); o.y = f2bf(v.y); o.z = f2bf(v.z); o.w = f2bf(v.w);
    *(ushort4*)(sgl + (size_t)i * 4) = o;
    return;
  }
  if (bid < 3504) {           // wpoA straight copy
    int i = (bid - 3396) * 256 + t;
    float4 v = *(const float4*)(Wpo + (size_t)i * 4);
    ushort4 o;
    o.x = f2bf(v.x); o.y = f2bf(v.y); o.z = f2bf(v.z); o.w = f2bf(v.w);
    *(ushort4*)(wpoA + (size_t)i * 4) = o;
    return;
  }
  if (bid < 3515) {           // bcat
    int idx = (bid - 3504) * 256 + t;
    if (idx < 2736) {
      float v;
      if (idx < 768) v = bq[idx];
      else if (idx < 1536) v = bk[idx - 768];
      else if (idx < 2304) v = bv[idx - 1536];
      else if (idx < 2448) v = bqp[idx - 2304];
      else if (idx < 2592) v = bkp[idx - 2448];
      else v = bvp[idx - 2592];
      bcat[idx] = v;
    }
    return;
  }
  {                           // wpbt [16][64]
    int idx = (bid - 3515) * 256 + t;
    int h = idx >> 6, k = idx & 63;
    wpbt[idx] = (h < 12) ? f2bf(Wpb[k * 12 + h]) : (unsigned short)0;
  }
}

// ---------------------------------------------------------------------------
// shared MFMA GEMM body (bf16 A/B), 128x128 tile, BK=32.
// EPI 0: outf = v (+ p0[col]) ; EPI 1: outb[col*912+768+row] = bf16(v)
// ---------------------------------------------------------------------------
template <int EPI>
__device__ __forceinline__ void gemm_dev(
    unsigned short* As, unsigned short* Bs,
    const unsigned short* __restrict__ A, int lda, int Mact,
    const unsigned short* __restrict__ Bt, int ldb, int Nact,
    int kt0, int ktn, int kmax,
    float* __restrict__ outf, unsigned short* __restrict__ outb, int ldc,
    const float* __restrict__ p0, int mb, int nb, int addbias)
{
  const int t = threadIdx.x;
  const int w = t >> 6, lane = t & 63;
  const int wr = w >> 1, wc = w & 1;
  const int lr = lane & 15, lc = lane >> 4;
  const int m0 = mb * 128, n0 = nb * 128;
  const int r0 = t >> 2, c0 = t & 3;
  const int r1 = r0 + 64;

  f32x4 acc[4][4] = {};
  u32x4 zz = {0u, 0u, 0u, 0u};
  u32x4 pa0, pa1, pq0, pq1;

#define LOAD_AB(KT)                                                              \
  do {                                                                           \
    int k0_ = (KT) * 32;                                                         \
    int g0_ = k0_ + c0 * 8;                                                      \
    pa0 = (g0_ < kmax && (m0 + r0) < Mact)                                       \
              ? *(const u32x4*)(A + (size_t)(m0 + r0) * lda + g0_) : zz;         \
    pa1 = (g0_ < kmax && (m0 + r1) < Mact)                                       \
              ? *(const u32x4*)(A + (size_t)(m0 + r1) * lda + g0_) : zz;         \
    pq0 = (g0_ < kmax && (n0 + r0) < Nact)                                       \
              ? *(const u32x4*)(Bt + (size_t)(n0 + r0) * ldb + g0_) : zz;        \
    pq1 = (g0_ < kmax && (n0 + r1) < Nact)                                       \
              ? *(const u32x4*)(Bt + (size_t)(n0 + r1) * ldb + g0_) : zz;        \
  } while (0)

  LOAD_AB(kt0);
  for (int kt = kt0; kt < kt0 + ktn; ++kt) {
    __syncthreads();
    ((u32x4*)As)[r0 * 4 + c0] = pa0;
    ((u32x4*)As)[r1 * 4 + c0] = pa1;
    ((u32x4*)Bs)[r0 * 4 + c0] = pq0;
    ((u32x4*)Bs)[r1 * 4 + c0] = pq1;
    __syncthreads();
    if (kt + 1 < kt0 + ktn) LOAD_AB(kt + 1);

    bf16x8 af[4], bfr[4];
#pragma unroll
    for (int mi = 0; mi < 4; ++mi) {
      int row = wr * 64 + mi * 16 + lr;
      af[mi] = *(const bf16x8*)(As + (row * 4 + lc) * 8);
    }
#pragma unroll
    for (int ni = 0; ni < 4; ++ni) {
      int row = wc * 64 + ni * 16 + lr;
      bfr[ni] = *(const bf16x8*)(Bs + (row * 4 + lc) * 8);
    }
#pragma unroll
    for (int mi = 0; mi < 4; ++mi)
#pragma unroll
      for (int ni = 0; ni < 4; ++ni)
        acc[mi][ni] = __builtin_amdgcn_mfma_f32_16x16x32_bf16(
            af[mi], bfr[ni], acc[mi][ni], 0, 0, 0);
  }
#undef LOAD_AB

#pragma unroll
  for (int mi = 0; mi < 4; ++mi) {
#pragma unroll
    for (int ni = 0; ni < 4; ++ni) {
#pragma unroll
      for (int r = 0; r < 4; ++r) {
        int row = m0 + wr * 64 + mi * 16 + lc * 4 + r;
        int col = n0 + wc * 64 + ni * 16 + lr;
        if (row < Mact && col < Nact) {
          float v = acc[mi][ni][r];
          if constexpr (EPI == 0) {
            outf[(size_t)row * ldc + col] = addbias ? (v + p0[col]) : v;
          } else {
            outb[(size_t)col * 912 + 768 + row] = f2bf(v);
          }
        }
      }
    }
  }
}

// ---------------------------------------------------------------------------
// fat kernel: [0..11] wfuse  [12..14] bfused  [15..366] proj(ks2)
// [367..4462] pairbias
// ---------------------------------------------------------------------------
__global__ __launch_bounds__(256) void fat_k(
    const unsigned short* __restrict__ sgl, const unsigned short* __restrict__ wcat,
    const float* __restrict__ bcat, float* __restrict__ qp2,
    const float* __restrict__ pair, const unsigned short* __restrict__ wpbt,
    const float* __restrict__ bpb, unsigned short* __restrict__ pb,
    const unsigned short* __restrict__ wpoA, unsigned short* __restrict__ WB,
    const float* __restrict__ bpo, const float* __restrict__ Wo,
    const float* __restrict__ bo, float* __restrict__ bfused)
{
  __shared__ unsigned short As[128 * 32];
  __shared__ unsigned short Bs[128 * 32];
  const int bid = blockIdx.x;
  const int t = threadIdx.x;

  if (bid < 12) {             // wfuse: Wfused = Wpo @ Wo -> WB[:,768:912]
    int mb = bid & 1, nb = bid >> 1;
    gemm_dev<1>(As, Bs, wpoA, 768, 144, WB, 912, 768, 0, 24, 768,
                nullptr, WB, 912, nullptr, mb, nb, 0);
    return;
  }
  if (bid < 15) {             // bfused[n] = bpo @ Wo + bo
    int n = (bid - 12) * 256 + t;
    float s = bo[n];
    for (int j = 0; j < 768; ++j) s += bpo[j] * Wo[(size_t)j * 768 + n];
    bfused[n] = s;
    return;
  }
  if (bid < 367) {            // proj, k-split 2
    int pbid = bid - 15;
    int zk = pbid / 176, rem = pbid % 176;
    int mb = rem & 7, nb = rem >> 3;
    gemm_dev<0>(As, Bs, sgl, 768, 1024, wcat, 768, 2736,
                zk * 12, 12, 768,
                qp2 + (size_t)zk * QPSLAB, nullptr, 2736, bcat, mb, nb, zk == 0);
    return;
  }
  // pairbias
  {
    const int w = t >> 6, lane = t & 63;
    const int lr = lane & 15, g = lane >> 4;
    bf16x8 wf0 = *(const bf16x8*)(wpbt + lr * 64 + g * 8);
    bf16x8 wf1 = *(const bf16x8*)(wpbt + lr * 64 + 32 + g * 8);
    const float bias_h = (lr < 12) ? bpb[lr] : 0.f;
    const int wid = (bid - 367) * 4 + w;
#pragma unroll
    for (int it = 0; it < 4; ++it) {
      int tile = wid * 4 + it;          // 0..65535
      int nm0 = tile * 16;
      const float* src = pair + (size_t)(nm0 + lr) * 64 + g * 8;
      float4 aA = *(const float4*)(src);
      float4 aB = *(const float4*)(src + 4);
      float4 aC = *(const float4*)(src + 32);
      float4 aD = *(const float4*)(src + 36);
      bf16x8 f0 = pack8(aA, aB);
      bf16x8 f1 = pack8(aC, aD);
      f32x4 c = {0.f, 0.f, 0.f, 0.f};
      c = __builtin_amdgcn_mfma_f32_16x16x32_bf16(f0, wf0, c, 0, 0, 0);
      c = __builtin_amdgcn_mfma_f32_16x16x32_bf16(f1, wf1, c, 0, 0, 0);
      if (lr < 12) {
        ushort4 o;
        o.x = f2bf(c[0] + bias_h);
        o.y = f2bf(c[1] + bias_h);
        o.z = f2bf(c[2] + bias_h);
        o.w = f2bf(c[3] + bias_h);
        *(ushort4*)(pb + ((size_t)lr << 20) + (size_t)nm0 + g * 4) = o;
      }
    }
  }
}

// ---------------------------------------------------------------------------
// rotate
// ---------------------------------------------------------------------------
__global__ __launch_bounds__(256) void rotate_k(
    const float* __restrict__ qp2, const float* __restrict__ rot,
    const float* __restrict__ trans,
    unsigned short* __restrict__ Acat, unsigned short* __restrict__ Bcat,
    unsigned short* __restrict__ VcatT, float* __restrict__ q2k2)
{
  const int n = blockIdx.x, t = threadIdx.x;
  __shared__ float R[9], T[3], rg[432];
  if (t < 9) R[t] = rot[n * 9 + t];
  if (t >= 9 && t < 12) T[t - 9] = trans[n * 3 + (t - 9)];
  __syncthreads();
  for (int s = t; s < 432; s += 256) {
    int j = s / 144, r = s % 144;
    int h = r / 12, wo = r % 12;
    int e = wo % 3;
    size_t base = (size_t)n * 2736 + 2304 + j * 144 + (r - e);
    float d0 = qp2[base + 0] + qp2[base + 0 + QPSLAB];
    float d1 = qp2[base + 1] + qp2[base + 1 + QPSLAB];
    float d2 = qp2[base + 2] + qp2[base + 2 + QPSLAB];
    float val = d0 * R[e] + d1 * R[3 + e] + d2 * R[6 + e] + T[e];
    rg[s] = val;
    unsigned short bv = f2bf(val);
    if (j == 0)      Acat[((size_t)h * NTOK + n) * 96 + 64 + wo] = bv;
    else if (j == 1) Bcat[((size_t)h * NTOK + n) * 96 + 64 + wo] = bv;
    else             VcatT[((size_t)h * 80 + 64 + wo) * NTOK + n] = bv;
  }
  __syncthreads();
  for (int s = t; s < 2304; s += 256) {
    int j = s / 768, c = s % 768;
    int h = c >> 6, cc = c & 63;
    size_t ix = (size_t)n * 2736 + s;
    unsigned short bv = f2bf(qp2[ix] + qp2[ix + QPSLAB]);
    if (j == 0)      Acat[((size_t)h * NTOK + n) * 96 + cc] = bv;
    else if (j == 1) Bcat[((size_t)h * NTOK + n) * 96 + cc] = bv;
    else             VcatT[((size_t)h * 80 + cc) * NTOK + n] = bv;
  }
  if (t < 240) {
    int h = t / 20, ix = 76 + t % 20;
    Acat[((size_t)h * NTOK + n) * 96 + ix] = 0;
    Bcat[((size_t)h * NTOK + n) * 96 + ix] = 0;
  }
  if (t >= 240 && t < 288) {
    int s = t - 240;
    int h = s / 4, rr = 76 + s % 4;
    VcatT[((size_t)h * 80 + rr) * NTOK + n] = 0;
  }
  if (t < 24) {
    int j = t / 12, h = t % 12;
    float sum = 0.f;
#pragma unroll
    for (int wo = 0; wo < 12; ++wo) {
      float v = rg[j * 144 + h * 12 + wo];
      sum += v * v;
    }
    q2k2[(size_t)(j * NH + h) * NTOK + n] = sum;
  }
}

// ---------------------------------------------------------------------------
// fused attention; writes per-chunk slab acc4[z][n][912] f32 directly in
// AW layout (col = h*64+cc scalar, 768+h*12+wo points).
// ---------------------------------------------------------------------------
__global__ __launch_bounds__(256) void attn_k(
    const unsigned short* __restrict__ pb, const unsigned short* __restrict__ Acat,
    const unsigned short* __restrict__ Bcat, const unsigned short* __restrict__ VcatT,
    const float* __restrict__ q2k2, float* __restrict__ acc4)
{
  __shared__ unsigned short Ls[64 * 256];
  __shared__ unsigned short Bs[128 * 104];
  const int t = threadIdx.x, w = t >> 6, lane = t & 63;
  const int lr = lane & 15, lc = lane >> 4;
  const int n0 = blockIdx.x * 64;
  const int m0 = blockIdx.y * 256;
  const int h  = blockIdx.z;

  const unsigned short* Pg = pb + ((size_t)h << 20) + (size_t)n0 * 1024 + m0;
#pragma unroll
  for (int i = 0; i < 8; ++i) {
    int idx = i * 256 + t;
    int row = idx >> 5, sl = idx & 31;
    u32x4 v = *(const u32x4*)(Pg + (size_t)row * 1024 + sl * 8);
    ((u32x4*)Ls)[row * 32 + (sl ^ (row & 7))] = v;
  }
  const unsigned short* Kg = Bcat + ((size_t)h * 1024 + m0) * 96;
#pragma unroll
  for (int i = 0; i < 6; ++i) {
    int idx = i * 256 + t;
    int row = idx / 12, c = idx % 12;
    u32x4 v = *(const u32x4*)(Kg + (size_t)row * 96 + c * 8);
    *(u32x4*)(Bs + row * 104 + c * 8) = v;
  }
  __syncthreads();

  bf16x8 qf[3];
  const unsigned short* Qg = Acat + ((size_t)h * 1024 + n0 + w * 16 + lr) * 96;
#pragma unroll
  for (int kk = 0; kk < 3; ++kk) qf[kk] = *(const bf16x8*)(Qg + kk * 32 + lc * 8);

  f32x4 sa[16];
#pragma unroll
  for (int ct = 0; ct < 16; ++ct) sa[ct] = (f32x4){0.f, 0.f, 0.f, 0.f};

#pragma unroll
  for (int ct = 0; ct < 8; ++ct)
#pragma unroll
    for (int kk = 0; kk < 3; ++kk) {
      bf16x8 kf = *(const bf16x8*)(Bs + (ct * 16 + lr) * 104 + kk * 32 + lc * 8);
      sa[ct] = __builtin_amdgcn_mfma_f32_16x16x32_bf16(kf, qf[kk], sa[ct], 0, 0, 0);
    }
  __syncthreads();
#pragma unroll
  for (int i = 0; i < 6; ++i) {
    int idx = i * 256 + t;
    int row = idx / 12, c = idx % 12;
    u32x4 v = *(const u32x4*)(Kg + (size_t)(128 + row) * 96 + c * 8);
    *(u32x4*)(Bs + row * 104 + c * 8) = v;
  }
  __syncthreads();
#pragma unroll
  for (int ct = 8; ct < 16; ++ct)
#pragma unroll
    for (int kk = 0; kk < 3; ++kk) {
      bf16x8 kf = *(const bf16x8*)(Bs + ((ct - 8) * 16 + lr) * 104 + kk * 32 + lc * 8);
      sa[ct] = __builtin_amdgcn_mfma_f32_16x16x32_bf16(kf, qf[kk], sa[ct], 0, 0, 0);
    }

  const int nrow = w * 16 + lr;
  const float q2v = q2k2[(size_t)h * 1024 + n0 + nrow];
  const float* k2b = q2k2 + 12288 + (size_t)h * 1024 + m0;
  float mx = -1e30f;
#pragma unroll
  for (int ct = 0; ct < 16; ++ct) {
    int sl = (ct * 2 + (lc >> 1)) ^ (nrow & 7);
    const unsigned short* p = Ls + nrow * 256 + sl * 8 + (lc & 1) * 4;
    ushort4 pv = *(const ushort4*)p;
    float4 k2v = *(const float4*)(k2b + ct * 16 + lc * 4);
    sa[ct][0] = 0.125f * sa[ct][0] + bf2f(pv.x) - 0.0625f * (q2v + k2v.x);
    sa[ct][1] = 0.125f * sa[ct][1] + bf2f(pv.y) - 0.0625f * (q2v + k2v.y);
    sa[ct][2] = 0.125f * sa[ct][2] + bf2f(pv.z) - 0.0625f * (q2v + k2v.z);
    sa[ct][3] = 0.125f * sa[ct][3] + bf2f(pv.w) - 0.0625f * (q2v + k2v.w);
    mx = fmaxf(mx, fmaxf(fmaxf(sa[ct][0], sa[ct][1]), fmaxf(sa[ct][2], sa[ct][3])));
  }
  mx = fmaxf(mx, __shfl_xor(mx, 16, 64));
  mx = fmaxf(mx, __shfl_xor(mx, 32, 64));
  float sm = 0.f;
#pragma unroll
  for (int ct = 0; ct < 16; ++ct)
#pragma unroll
    for (int r = 0; r < 4; ++r) { sa[ct][r] = __expf(sa[ct][r] - mx); sm += sa[ct][r]; }
  sm += __shfl_xor(sm, 16, 64);
  sm += __shfl_xor(sm, 32, 64);
  float inv = 1.0f / sm;
#pragma unroll
  for (int ct = 0; ct < 16; ++ct) {
    int sl = (ct * 2 + (lc >> 1)) ^ (nrow & 7);
    unsigned short* p = Ls + nrow * 256 + sl * 8 + (lc & 1) * 4;
    ushort4 pw;
    pw.x = f2bf(sa[ct][0] * inv); pw.y = f2bf(sa[ct][1] * inv);
    pw.z = f2bf(sa[ct][2] * inv); pw.w = f2bf(sa[ct][3] * inv);
    *(ushort4*)p = pw;
  }
  __syncthreads();

  f32x4 acc[5];
#pragma unroll
  for (int nf = 0; nf < 5; ++nf) acc[nf] = (f32x4){0.f, 0.f, 0.f, 0.f};
  const unsigned short* Vg = VcatT + (size_t)h * 80 * NTOK + m0;
#pragma unroll
  for (int kk = 0; kk < 8; ++kk) {
    int row = w * 16 + lr;
    int sl = (kk * 4 + lc) ^ (row & 7);
    bf16x8 a = *(const bf16x8*)(Ls + row * 256 + sl * 8);
#pragma unroll
    for (int nf = 0; nf < 5; ++nf) {
      int c = nf * 16 + lr;
      bf16x8 b = *(const bf16x8*)(Vg + (size_t)c * NTOK + kk * 32 + lc * 8);
      acc[nf] = __builtin_amdgcn_mfma_f32_16x16x32_bf16(a, b, acc[nf], 0, 0, 0);
    }
  }
  float* outz = acc4 + (size_t)blockIdx.y * SLA;
#pragma unroll
  for (int nf = 0; nf < 4; ++nf)
#pragma unroll
    for (int r = 0; r < 4; ++r) {
      int orow = n0 + w * 16 + lc * 4 + r;
      outz[(size_t)orow * 912 + h * 64 + nf * 16 + lr] = acc[nf][r];
    }
  if (lr < 12)
#pragma unroll
    for (int r = 0; r < 4; ++r) {
      int orow = n0 + w * 16 + lc * 4 + r;
      outz[(size_t)orow * 912 + 768 + h * 12 + lr] = acc[4][r];
    }
}

// ---------------------------------------------------------------------------
// tail gemm (k-split 8): A = bf16(sum of 4 f32 slabs) staged in-register.
// outpre[z] = A @ WB^T
// ---------------------------------------------------------------------------
__global__ __launch_bounds__(256) void tail_k(
    const float* __restrict__ acc4, const unsigned short* __restrict__ WB,
    float* __restrict__ outpre)
{
  __shared__ unsigned short As[128 * 32];
  __shared__ unsigned short Bs[128 * 32];
  const int t = threadIdx.x, w = t >> 6, lane = t & 63;
  const int wr = w >> 1, wc = w & 1;
  const int lr = lane & 15, lc = lane >> 4;
  const int m0 = blockIdx.x * 128, n0 = blockIdx.y * 128;
  const int z = blockIdx.z;
  const int kt0 = (z * 29) >> 3, kt1 = ((z + 1) * 29) >> 3;
  const int r0 = t >> 2, c0 = t & 3, r1 = r0 + 64;

  f32x4 acc[4][4] = {};
  u32x4 zz = {0u, 0u, 0u, 0u};
  bf16x8 zb = {0, 0, 0, 0, 0, 0, 0, 0};
  bf16x8 pa0, pa1; u32x4 pq0, pq1;

#define LOAD_T(KT)                                                               \
  do {                                                                           \
    int g0_ = (KT) * 32 + c0 * 8;                                                \
    pa0 = (g0_ < 912) ? sum4pack(acc4 + (size_t)(m0 + r0) * 912 + g0_) : zb;     \
    pa1 = (g0_ < 912) ? sum4pack(acc4 + (size_t)(m0 + r1) * 912 + g0_) : zb;     \
    pq0 = (g0_ < 912) ? *(const u32x4*)(WB + (size_t)(n0 + r0) * 912 + g0_) : zz; \
    pq1 = (g0_ < 912) ? *(const u32x4*)(WB + (size_t)(n0 + r1) * 912 + g0_) : zz; \
  } while (0)

  LOAD_T(kt0);
  for (int kt = kt0; kt < kt1; ++kt) {
    __syncthreads();
    *(bf16x8*)(As + (r0 * 4 + c0) * 8) = pa0;
    *(bf16x8*)(As + (r1 * 4 + c0) * 8) = pa1;
    ((u32x4*)Bs)[r0 * 4 + c0] = pq0;
    ((u32x4*)Bs)[r1 * 4 + c0] = pq1;
    __syncthreads();
    if (kt + 1 < kt1) LOAD_T(kt + 1);

    bf16x8 af[4], bfr[4];
#pragma unroll
    for (int mi = 0; mi < 4; ++mi) {
      int row = wr * 64 + mi * 16 + lr;
      af[mi] = *(const bf16x8*)(As + (row * 4 + lc) * 8);
    }
#pragma unroll
    for (int ni = 0; ni < 4; ++ni) {
      int row = wc * 64 + ni * 16 + lr;
      bfr[ni] = *(const bf16x8*)(Bs + (row * 4 + lc) * 8);
    }
#pragma unroll
    for (int mi = 0; mi < 4; ++mi)
#pragma unroll
      for (int ni = 0; ni < 4; ++ni)
        acc[mi][ni] = __builtin_amdgcn_mfma_f32_16x16x32_bf16(
            af[mi], bfr[ni], acc[mi][ni], 0, 0, 0);
  }
#undef LOAD_T

  float* outz = outpre + (size_t)z * 786432;
#pragma unroll
  for (int mi = 0; mi < 4; ++mi)
#pragma unroll
    for (int ni = 0; ni < 4; ++ni)
#pragma unroll
      for (int r = 0; r < 4; ++r) {
        int row = m0 + wr * 64 + mi * 16 + lc * 4 + r;
        int col = n0 + wc * 64 + ni * 16 + lr;
        outz[(size_t)row * 768 + col] = acc[mi][ni][r];
      }
}

// ---------------------------------------------------------------------------
// layernorm(single + sum(8 outpre slabs) + bfused) -> d_out
// ---------------------------------------------------------------------------
__global__ __launch_bounds__(256) void ln_k(
    const float* __restrict__ single, const float* __restrict__ outpre,
    const float* __restrict__ bfused, const float* __restrict__ g,
    const float* __restrict__ b, float* __restrict__ out)
{
  const int row = blockIdx.x, t = threadIdx.x;
  __shared__ float red[8];
  size_t base = (size_t)row * 768;
  const size_t SL = 786432;
  float x[3];
#pragma unroll
  for (int j = 0; j < 3; ++j) {
    int c = t + j * 256;
    float v = single[base + c] + bfused[c];
#pragma unroll
    for (int z = 0; z < 8; ++z) v += outpre[base + c + (size_t)z * SL];
    x[j] = v;
  }
  float s = x[0] + x[1] + x[2];
#pragma unroll
  for (int off = 32; off; off >>= 1) s += __shfl_xor(s, off, 64);
  if ((t & 63) == 0) red[t >> 6] = s;
  __syncthreads();
  float mu = (red[0] + red[1] + red[2] + red[3]) * (1.0f / 768.0f);
  float d0 = x[0] - mu, d1 = x[1] - mu, d2 = x[2] - mu;
  float vs = d0 * d0 + d1 * d1 + d2 * d2;
#pragma unroll
  for (int off = 32; off; off >>= 1) vs += __shfl_xor(vs, off, 64);
  if ((t & 63) == 0) red[4 + (t >> 6)] = vs;
  __syncthreads();
  float var = (red[4] + red[5] + red[6] + red[7]) * (1.0f / 768.0f);
  float rs = rsqrtf(var + 1e-5f);
  out[base + t]       = d0 * rs * g[t]       + b[t];
  out[base + t + 256] = d1 * rs * g[t + 256] + b[t + 256];
  out[base + t + 512] = d2 * rs * g[t + 512] + b[t + 512];
}

// ---------------------------------------------------------------------------
extern "C" void kernel_launch(void* const* d_in, const int* in_sizes, int n_in,
                              void* d_out, int out_size, void* d_ws, size_t ws_size,
                              hipStream_t stream)
{
  (void)in_sizes; (void)n_in; (void)out_size; (void)ws_size;
  const float* single = (const float*)d_in[0];
  const float* pair   = (const float*)d_in[1];
  const float* rot    = (const float*)d_in[2];
  const float* trans  = (const float*)d_in[3];
  const float* Wq  = (const float*)d_in[4];  const float* bq  = (const float*)d_in[5];
  const float* Wk  = (const float*)d_in[6];  const float* bk  = (const float*)d_in[7];
  const float* Wv  = (const float*)d_in[8];  const float* bv  = (const float*)d_in[9];
  const float* Wpb = (const float*)d_in[10]; const float* bpb = (const float*)d_in[11];
  const float* Wqp = (const float*)d_in[12]; const float* bqp = (const float*)d_in[13];
  const float* Wkp = (const float*)d_in[14]; const float* bkp = (const float*)d_in[15];
  const float* Wvp = (const float*)d_in[16]; const float* bvp = (const float*)d_in[17];
  const float* Wo  = (const float*)d_in[18]; const float* bo  = (const float*)d_in[19];
  const float* Wpo = (const float*)d_in[20]; const float* bpo = (const float*)d_in[21];
  const float* lng = (const float*)d_in[22]; const float* lnb = (const float*)d_in[23];

  char* ws = (char*)d_ws;
  unsigned short* sgl    = (unsigned short*)(ws + 0);
  unsigned short* wcat   = (unsigned short*)(ws + 1572864);
  unsigned short* wpoA   = (unsigned short*)(ws + 5775360);
  unsigned short* WB     = (unsigned short*)(ws + 5996544);
  float*          bcat   = (float*)(ws + 7397376);
  unsigned short* wpbt   = (unsigned short*)(ws + 7408320);
  float*          bfused = (float*)(ws + 7410432);
  float*          qp2    = (float*)(ws + 7413504);
  unsigned short* Acat   = (unsigned short*)(ws + 29826816);
  unsigned short* Bcat   = (unsigned short*)(ws + 32186112);
  unsigned short* VcatT  = (unsigned short*)(ws + 34545408);
  float*          q2k2   = (float*)(ws + 36511488);
  unsigned short* pb     = (unsigned short*)(ws + 36609792);
  float*          acc4   = (float*)(ws + 61775616);   // [4][1024][912] f32
  float*          outpre = (float*)(ws + 76717824);   // [8][1024][768] f32

  prep_k<<<3519, 256, 0, stream>>>(single, Wq, Wk, Wv, Wqp, Wkp, Wvp, Wpo, Wo,
                                   Wpb, bq, bk, bv, bqp, bkp, bvp,
                                   sgl, wcat, WB, wpoA, bcat, wpbt);

  // PROBE: fat_k x3 (idempotent). dur_us = base + 2*T_fat.
  fat_k<<<4463, 256, 0, stream>>>(sgl, wcat, bcat, qp2, pair, wpbt, bpb, pb,
                                  wpoA, WB, bpo, Wo, bo, bfused);
  fat_k<<<4463, 256, 0, stream>>>(sgl, wcat, bcat, qp2, pair, wpbt, bpb, pb,
                                  wpoA, WB, bpo, Wo, bo, bfused);
  fat_k<<<4463, 256, 0, stream>>>(sgl, wcat, bcat, qp2, pair, wpbt, bpb, pb,
                                  wpoA, WB, bpo, Wo, bo, bfused);

  rotate_k<<<1024, 256, 0, stream>>>(qp2, rot, trans, Acat, Bcat, VcatT, q2k2);

  attn_k<<<dim3(16, 4, 12), 256, 0, stream>>>(pb, Acat, Bcat, VcatT, q2k2, acc4);

  tail_k<<<dim3(8, 6, 8), 256, 0, stream>>>(acc4, WB, outpre);

  ln_k<<<1024, 256, 0, stream>>>(single, outpre, bfused, lng, lnb, (float*)d_out);
}

// Round 6
// 198.332 us; speedup vs baseline: 1.7324x; 1.7324x over previous
//
#include <hip/hip_runtime.h>
#include <stdint.h>

#define NTOK 1024
#define NH 12
#define QPSLAB 2801664   // 1024*2736
#define SLA 933888       // 1024*912 (f32 elems per acc slab)

typedef short bf16x8 __attribute__((ext_vector_type(8)));
typedef float f32x4 __attribute__((ext_vector_type(4)));
typedef uint32_t u32x4 __attribute__((ext_vector_type(4)));

__device__ __forceinline__ unsigned short f2bf(float f) {
  union { float f; uint32_t u; } x; x.f = f;
  uint32_t r = x.u + 0x7FFFu + ((x.u >> 16) & 1u);
  return (unsigned short)(r >> 16);
}
__device__ __forceinline__ float bf2f(unsigned short u) {
  union { uint32_t u; float f; } x; x.u = ((uint32_t)u) << 16;
  return x.f;
}
__device__ __forceinline__ bf16x8 pack8(float4 a, float4 b) {
  bf16x8 r;
  r[0] = (short)f2bf(a.x); r[1] = (short)f2bf(a.y);
  r[2] = (short)f2bf(a.z); r[3] = (short)f2bf(a.w);
  r[4] = (short)f2bf(b.x); r[5] = (short)f2bf(b.y);
  r[6] = (short)f2bf(b.z); r[7] = (short)f2bf(b.w);
  return r;
}
// sum 4 f32 slabs (stride SLA) of 8 consecutive elems -> bf16x8
__device__ __forceinline__ bf16x8 sum4pack(const float* __restrict__ p) {
  float4 s0 = *(const float4*)(p);
  float4 s1 = *(const float4*)(p + 4);
#pragma unroll
  for (int z = 1; z < 4; ++z) {
    const float* q = p + (size_t)z * SLA;
    float4 a = *(const float4*)(q), b = *(const float4*)(q + 4);
    s0.x += a.x; s0.y += a.y; s0.z += a.z; s0.w += a.w;
    s1.x += b.x; s1.y += b.y; s1.z += b.z; s1.w += b.w;
  }
  return pack8(s0, s1);
}

// ---------------------------------------------------------------------------
// prep: LDS-tiled transposes (coalesced both sides) + vectorized copies.
// ---------------------------------------------------------------------------
__global__ __launch_bounds__(256) void prep_k(
    const float* __restrict__ single, const float* __restrict__ Wq,
    const float* __restrict__ Wk, const float* __restrict__ Wv,
    const float* __restrict__ Wqp, const float* __restrict__ Wkp,
    const float* __restrict__ Wvp, const float* __restrict__ Wpo,
    const float* __restrict__ Wo, const float* __restrict__ Wpb,
    const float* __restrict__ bq, const float* __restrict__ bk,
    const float* __restrict__ bv, const float* __restrict__ bqp,
    const float* __restrict__ bkp, const float* __restrict__ bvp,
    unsigned short* __restrict__ sgl, unsigned short* __restrict__ wcat,
    unsigned short* __restrict__ WB, unsigned short* __restrict__ wpoA,
    float* __restrict__ bcat, unsigned short* __restrict__ wpbt)
{
  const int bid = blockIdx.x, t = threadIdx.x;
  if (bid < 2628) {
    __shared__ unsigned short tl[16][72];
    int b = bid;
    const float* src; unsigned short* dst; int N, dstld, rowbase;
    if (b < 1728) {
      int j = b / 576; b -= j * 576;
      src = (j == 0) ? Wq : (j == 1) ? Wk : Wv;
      N = 768; dst = wcat; dstld = 768; rowbase = j * 768;
    } else if (b < 2052) {
      b -= 1728; int j = b / 108; b -= j * 108;
      src = (j == 0) ? Wqp : (j == 1) ? Wkp : Wvp;
      N = 144; dst = wcat; dstld = 768; rowbase = 2304 + j * 144;
    } else {
      b -= 2052; src = Wo; N = 768; dst = WB; dstld = 912; rowbase = 0;
    }
    const int k0 = (b % 12) * 64, n0 = (b / 12) * 16;
#pragma unroll
    for (int i = 0; i < 4; ++i) {
      int kk = (t >> 4) + i * 16;
      int nn = t & 15;
      tl[nn][kk] = f2bf(src[(size_t)(k0 + kk) * N + n0 + nn]);
    }
    __syncthreads();
#pragma unroll
    for (int i = 0; i < 4; ++i) {
      int kk = t & 63;
      int nn = (t >> 6) + i * 4;
      dst[(size_t)(rowbase + n0 + nn) * dstld + k0 + kk] = tl[nn][kk];
    }
    return;
  }
  if (bid < 3396) {           // sgl float4 copy
    int i = (bid - 2628) * 256 + t;
    float4 v = *(const float4*)(single + (size_t)i * 4);
    ushort4 o;
    o.x = f2bf(v.x); o.y = f2bf(v.y); o.z = f2bf(v.z); o.w = f2bf(v.w);
    *(ushort4*)(sgl + (size_t)i * 4) = o;
    return;
  }
  if (bid < 3504) {           // wpoA straight copy
    int i = (bid - 3396) * 256 + t;
    float4 v = *(const float4*)(Wpo + (size_t)i * 4);
    ushort4 o;
    o.x = f2bf(v.x); o.y = f2bf(v.y); o.z = f2bf(v.z); o.w = f2bf(v.w);
    *(ushort4*)(wpoA + (size_t)i * 4) = o;
    return;
  }
  if (bid < 3515) {           // bcat
    int idx = (bid - 3504) * 256 + t;
    if (idx < 2736) {
      float v;
      if (idx < 768) v = bq[idx];
      else if (idx < 1536) v = bk[idx - 768];
      else if (idx < 2304) v = bv[idx - 1536];
      else if (idx < 2448) v = bqp[idx - 2304];
      else if (idx < 2592) v = bkp[idx - 2448];
      else v = bvp[idx - 2592];
      bcat[idx] = v;
    }
    return;
  }
  {                           // wpbt [16][64]
    int idx = (bid - 3515) * 256 + t;
    int h = idx >> 6, k = idx & 63;
    wpbt[idx] = (h < 12) ? f2bf(Wpb[k * 12 + h]) : (unsigned short)0;
  }
}

// ---------------------------------------------------------------------------
// shared MFMA GEMM body (bf16 A/B), 128x128 tile, BK=32.
// EPI 0: outf = v (+ p0[col]) ; EPI 1: outb[col*912+768+row] = bf16(v)
// ---------------------------------------------------------------------------
template <int EPI>
__device__ __forceinline__ void gemm_dev(
    unsigned short* As, unsigned short* Bs,
    const unsigned short* __restrict__ A, int lda, int Mact,
    const unsigned short* __restrict__ Bt, int ldb, int Nact,
    int kt0, int ktn, int kmax,
    float* __restrict__ outf, unsigned short* __restrict__ outb, int ldc,
    const float* __restrict__ p0, int mb, int nb, int addbias)
{
  const int t = threadIdx.x;
  const int w = t >> 6, lane = t & 63;
  const int wr = w >> 1, wc = w & 1;
  const int lr = lane & 15, lc = lane >> 4;
  const int m0 = mb * 128, n0 = nb * 128;
  const int r0 = t >> 2, c0 = t & 3;
  const int r1 = r0 + 64;

  f32x4 acc[4][4] = {};
  u32x4 zz = {0u, 0u, 0u, 0u};
  u32x4 pa0, pa1, pq0, pq1;

#define LOAD_AB(KT)                                                              \
  do {                                                                           \
    int k0_ = (KT) * 32;                                                         \
    int g0_ = k0_ + c0 * 8;                                                      \
    pa0 = (g0_ < kmax && (m0 + r0) < Mact)                                       \
              ? *(const u32x4*)(A + (size_t)(m0 + r0) * lda + g0_) : zz;         \
    pa1 = (g0_ < kmax && (m0 + r1) < Mact)                                       \
              ? *(const u32x4*)(A + (size_t)(m0 + r1) * lda + g0_) : zz;         \
    pq0 = (g0_ < kmax && (n0 + r0) < Nact)                                       \
              ? *(const u32x4*)(Bt + (size_t)(n0 + r0) * ldb + g0_) : zz;        \
    pq1 = (g0_ < kmax && (n0 + r1) < Nact)                                       \
              ? *(const u32x4*)(Bt + (size_t)(n0 + r1) * ldb + g0_) : zz;        \
  } while (0)

  LOAD_AB(kt0);
  for (int kt = kt0; kt < kt0 + ktn; ++kt) {
    __syncthreads();
    ((u32x4*)As)[r0 * 4 + c0] = pa0;
    ((u32x4*)As)[r1 * 4 + c0] = pa1;
    ((u32x4*)Bs)[r0 * 4 + c0] = pq0;
    ((u32x4*)Bs)[r1 * 4 + c0] = pq1;
    __syncthreads();
    if (kt + 1 < kt0 + ktn) LOAD_AB(kt + 1);

    bf16x8 af[4], bfr[4];
#pragma unroll
    for (int mi = 0; mi < 4; ++mi) {
      int row = wr * 64 + mi * 16 + lr;
      af[mi] = *(const bf16x8*)(As + (row * 4 + lc) * 8);
    }
#pragma unroll
    for (int ni = 0; ni < 4; ++ni) {
      int row = wc * 64 + ni * 16 + lr;
      bfr[ni] = *(const bf16x8*)(Bs + (row * 4 + lc) * 8);
    }
#pragma unroll
    for (int mi = 0; mi < 4; ++mi)
#pragma unroll
      for (int ni = 0; ni < 4; ++ni)
        acc[mi][ni] = __builtin_amdgcn_mfma_f32_16x16x32_bf16(
            af[mi], bfr[ni], acc[mi][ni], 0, 0, 0);
  }
#undef LOAD_AB

#pragma unroll
  for (int mi = 0; mi < 4; ++mi) {
#pragma unroll
    for (int ni = 0; ni < 4; ++ni) {
#pragma unroll
      for (int r = 0; r < 4; ++r) {
        int row = m0 + wr * 64 + mi * 16 + lc * 4 + r;
        int col = n0 + wc * 64 + ni * 16 + lr;
        if (row < Mact && col < Nact) {
          float v = acc[mi][ni][r];
          if constexpr (EPI == 0) {
            outf[(size_t)row * ldc + col] = addbias ? (v + p0[col]) : v;
          } else {
            outb[(size_t)col * 912 + 768 + row] = f2bf(v);
          }
        }
      }
    }
  }
}

// ---------------------------------------------------------------------------
// projfat kernel: [0..11] wfuse  [12..14] bfused  [15..366] proj(ks2)
// (pairbias un-merged: its blocks were VGPR-starved by gemm_dev's allocation)
// ---------------------------------------------------------------------------
__global__ __launch_bounds__(256) void projfat_k(
    const unsigned short* __restrict__ sgl, const unsigned short* __restrict__ wcat,
    const float* __restrict__ bcat, float* __restrict__ qp2,
    const unsigned short* __restrict__ wpoA, unsigned short* __restrict__ WB,
    const float* __restrict__ bpo, const float* __restrict__ Wo,
    const float* __restrict__ bo, float* __restrict__ bfused)
{
  __shared__ unsigned short As[128 * 32];
  __shared__ unsigned short Bs[128 * 32];
  const int bid = blockIdx.x;
  const int t = threadIdx.x;

  if (bid < 12) {             // wfuse: Wfused = Wpo @ Wo -> WB[:,768:912]
    int mb = bid & 1, nb = bid >> 1;
    gemm_dev<1>(As, Bs, wpoA, 768, 144, WB, 912, 768, 0, 24, 768,
                nullptr, WB, 912, nullptr, mb, nb, 0);
    return;
  }
  if (bid < 15) {             // bfused[n] = bpo @ Wo + bo
    int n = (bid - 12) * 256 + t;
    float s = bo[n];
    for (int j = 0; j < 768; ++j) s += bpo[j] * Wo[(size_t)j * 768 + n];
    bfused[n] = s;
    return;
  }
  {                           // proj, k-split 2
    int pbid = bid - 15;
    int zk = pbid / 176, rem = pbid % 176;
    int mb = rem & 7, nb = rem >> 3;
    gemm_dev<0>(As, Bs, sgl, 768, 1024, wcat, 768, 2736,
                zk * 12, 12, 768,
                qp2 + (size_t)zk * QPSLAB, nullptr, 2736, bcat, mb, nb, zk == 0);
  }
}

// ---------------------------------------------------------------------------
// pairbias standalone (high occupancy): pb[h][nm] = bf16(pair.Wpb[:,h]+bpb[h])
// ---------------------------------------------------------------------------
__global__ __launch_bounds__(256, 4) void pairbias_k(
    const float* __restrict__ pair, const unsigned short* __restrict__ wpbt,
    const float* __restrict__ bpb, unsigned short* __restrict__ pb)
{
  const int t = threadIdx.x, w = t >> 6, lane = t & 63;
  const int lr = lane & 15, g = lane >> 4;
  bf16x8 wf0 = *(const bf16x8*)(wpbt + lr * 64 + g * 8);
  bf16x8 wf1 = *(const bf16x8*)(wpbt + lr * 64 + 32 + g * 8);
  const float bias_h = (lr < 12) ? bpb[lr] : 0.f;
  const int wid = blockIdx.x * 4 + w;
#pragma unroll
  for (int it = 0; it < 4; ++it) {
    int tile = wid * 4 + it;            // 0..65535
    int nm0 = tile * 16;
    const float* src = pair + (size_t)(nm0 + lr) * 64 + g * 8;
    float4 aA = *(const float4*)(src);
    float4 aB = *(const float4*)(src + 4);
    float4 aC = *(const float4*)(src + 32);
    float4 aD = *(const float4*)(src + 36);
    bf16x8 f0 = pack8(aA, aB);
    bf16x8 f1 = pack8(aC, aD);
    f32x4 c = {0.f, 0.f, 0.f, 0.f};
    c = __builtin_amdgcn_mfma_f32_16x16x32_bf16(f0, wf0, c, 0, 0, 0);
    c = __builtin_amdgcn_mfma_f32_16x16x32_bf16(f1, wf1, c, 0, 0, 0);
    if (lr < 12) {
      ushort4 o;
      o.x = f2bf(c[0] + bias_h);
      o.y = f2bf(c[1] + bias_h);
      o.z = f2bf(c[2] + bias_h);
      o.w = f2bf(c[3] + bias_h);
      *(ushort4*)(pb + ((size_t)lr << 20) + (size_t)nm0 + g * 4) = o;
    }
  }
}

// ---------------------------------------------------------------------------
// rotate
// ---------------------------------------------------------------------------
__global__ __launch_bounds__(256) void rotate_k(
    const float* __restrict__ qp2, const float* __restrict__ rot,
    const float* __restrict__ trans,
    unsigned short* __restrict__ Acat, unsigned short* __restrict__ Bcat,
    unsigned short* __restrict__ VcatT, float* __restrict__ q2k2)
{
  const int n = blockIdx.x, t = threadIdx.x;
  __shared__ float R[9], T[3], rg[432];
  if (t < 9) R[t] = rot[n * 9 + t];
  if (t >= 9 && t < 12) T[t - 9] = trans[n * 3 + (t - 9)];
  __syncthreads();
  for (int s = t; s < 432; s += 256) {
    int j = s / 144, r = s % 144;
    int h = r / 12, wo = r % 12;
    int e = wo % 3;
    size_t base = (size_t)n * 2736 + 2304 + j * 144 + (r - e);
    float d0 = qp2[base + 0] + qp2[base + 0 + QPSLAB];
    float d1 = qp2[base + 1] + qp2[base + 1 + QPSLAB];
    float d2 = qp2[base + 2] + qp2[base + 2 + QPSLAB];
    float val = d0 * R[e] + d1 * R[3 + e] + d2 * R[6 + e] + T[e];
    rg[s] = val;
    unsigned short bv = f2bf(val);
    if (j == 0)      Acat[((size_t)h * NTOK + n) * 96 + 64 + wo] = bv;
    else if (j == 1) Bcat[((size_t)h * NTOK + n) * 96 + 64 + wo] = bv;
    else             VcatT[((size_t)h * 80 + 64 + wo) * NTOK + n] = bv;
  }
  __syncthreads();
  for (int s = t; s < 2304; s += 256) {
    int j = s / 768, c = s % 768;
    int h = c >> 6, cc = c & 63;
    size_t ix = (size_t)n * 2736 + s;
    unsigned short bv = f2bf(qp2[ix] + qp2[ix + QPSLAB]);
    if (j == 0)      Acat[((size_t)h * NTOK + n) * 96 + cc] = bv;
    else if (j == 1) Bcat[((size_t)h * NTOK + n) * 96 + cc] = bv;
    else             VcatT[((size_t)h * 80 + cc) * NTOK + n] = bv;
  }
  if (t < 240) {
    int h = t / 20, ix = 76 + t % 20;
    Acat[((size_t)h * NTOK + n) * 96 + ix] = 0;
    Bcat[((size_t)h * NTOK + n) * 96 + ix] = 0;
  }
  if (t >= 240 && t < 288) {
    int s = t - 240;
    int h = s / 4, rr = 76 + s % 4;
    VcatT[((size_t)h * 80 + rr) * NTOK + n] = 0;
  }
  if (t < 24) {
    int j = t / 12, h = t % 12;
    float sum = 0.f;
#pragma unroll
    for (int wo = 0; wo < 12; ++wo) {
      float v = rg[j * 144 + h * 12 + wo];
      sum += v * v;
    }
    q2k2[(size_t)(j * NH + h) * NTOK + n] = sum;
  }
}

// ---------------------------------------------------------------------------
// fused attention; writes per-chunk slab acc4[z][n][912] f32 directly in
// AW layout (col = h*64+cc scalar, 768+h*12+wo points).
// ---------------------------------------------------------------------------
__global__ __launch_bounds__(256) void attn_k(
    const unsigned short* __restrict__ pb, const unsigned short* __restrict__ Acat,
    const unsigned short* __restrict__ Bcat, const unsigned short* __restrict__ VcatT,
    const float* __restrict__ q2k2, float* __restrict__ acc4)
{
  __shared__ unsigned short Ls[64 * 256];
  __shared__ unsigned short Bs[128 * 104];
  const int t = threadIdx.x, w = t >> 6, lane = t & 63;
  const int lr = lane & 15, lc = lane >> 4;
  const int n0 = blockIdx.x * 64;
  const int m0 = blockIdx.y * 256;
  const int h  = blockIdx.z;

  const unsigned short* Pg = pb + ((size_t)h << 20) + (size_t)n0 * 1024 + m0;
#pragma unroll
  for (int i = 0; i < 8; ++i) {
    int idx = i * 256 + t;
    int row = idx >> 5, sl = idx & 31;
    u32x4 v = *(const u32x4*)(Pg + (size_t)row * 1024 + sl * 8);
    ((u32x4*)Ls)[row * 32 + (sl ^ (row & 7))] = v;
  }
  const unsigned short* Kg = Bcat + ((size_t)h * 1024 + m0) * 96;
#pragma unroll
  for (int i = 0; i < 6; ++i) {
    int idx = i * 256 + t;
    int row = idx / 12, c = idx % 12;
    u32x4 v = *(const u32x4*)(Kg + (size_t)row * 96 + c * 8);
    *(u32x4*)(Bs + row * 104 + c * 8) = v;
  }
  __syncthreads();

  bf16x8 qf[3];
  const unsigned short* Qg = Acat + ((size_t)h * 1024 + n0 + w * 16 + lr) * 96;
#pragma unroll
  for (int kk = 0; kk < 3; ++kk) qf[kk] = *(const bf16x8*)(Qg + kk * 32 + lc * 8);

  f32x4 sa[16];
#pragma unroll
  for (int ct = 0; ct < 16; ++ct) sa[ct] = (f32x4){0.f, 0.f, 0.f, 0.f};

#pragma unroll
  for (int ct = 0; ct < 8; ++ct)
#pragma unroll
    for (int kk = 0; kk < 3; ++kk) {
      bf16x8 kf = *(const bf16x8*)(Bs + (ct * 16 + lr) * 104 + kk * 32 + lc * 8);
      sa[ct] = __builtin_amdgcn_mfma_f32_16x16x32_bf16(kf, qf[kk], sa[ct], 0, 0, 0);
    }
  __syncthreads();
#pragma unroll
  for (int i = 0; i < 6; ++i) {
    int idx = i * 256 + t;
    int row = idx / 12, c = idx % 12;
    u32x4 v = *(const u32x4*)(Kg + (size_t)(128 + row) * 96 + c * 8);
    *(u32x4*)(Bs + row * 104 + c * 8) = v;
  }
  __syncthreads();
#pragma unroll
  for (int ct = 8; ct < 16; ++ct)
#pragma unroll
    for (int kk = 0; kk < 3; ++kk) {
      bf16x8 kf = *(const bf16x8*)(Bs + ((ct - 8) * 16 + lr) * 104 + kk * 32 + lc * 8);
      sa[ct] = __builtin_amdgcn_mfma_f32_16x16x32_bf16(kf, qf[kk], sa[ct], 0, 0, 0);
    }

  const int nrow = w * 16 + lr;
  const float q2v = q2k2[(size_t)h * 1024 + n0 + nrow];
  const float* k2b = q2k2 + 12288 + (size_t)h * 1024 + m0;
  float mx = -1e30f;
#pragma unroll
  for (int ct = 0; ct < 16; ++ct) {
    int sl = (ct * 2 + (lc >> 1)) ^ (nrow & 7);
    const unsigned short* p = Ls + nrow * 256 + sl * 8 + (lc & 1) * 4;
    ushort4 pv = *(const ushort4*)p;
    float4 k2v = *(const float4*)(k2b + ct * 16 + lc * 4);
    sa[ct][0] = 0.125f * sa[ct][0] + bf2f(pv.x) - 0.0625f * (q2v + k2v.x);
    sa[ct][1] = 0.125f * sa[ct][1] + bf2f(pv.y) - 0.0625f * (q2v + k2v.y);
    sa[ct][2] = 0.125f * sa[ct][2] + bf2f(pv.z) - 0.0625f * (q2v + k2v.z);
    sa[ct][3] = 0.125f * sa[ct][3] + bf2f(pv.w) - 0.0625f * (q2v + k2v.w);
    mx = fmaxf(mx, fmaxf(fmaxf(sa[ct][0], sa[ct][1]), fmaxf(sa[ct][2], sa[ct][3])));
  }
  mx = fmaxf(mx, __shfl_xor(mx, 16, 64));
  mx = fmaxf(mx, __shfl_xor(mx, 32, 64));
  float sm = 0.f;
#pragma unroll
  for (int ct = 0; ct < 16; ++ct)
#pragma unroll
    for (int r = 0; r < 4; ++r) { sa[ct][r] = __expf(sa[ct][r] - mx); sm += sa[ct][r]; }
  sm += __shfl_xor(sm, 16, 64);
  sm += __shfl_xor(sm, 32, 64);
  float inv = 1.0f / sm;
#pragma unroll
  for (int ct = 0; ct < 16; ++ct) {
    int sl = (ct * 2 + (lc >> 1)) ^ (nrow & 7);
    unsigned short* p = Ls + nrow * 256 + sl * 8 + (lc & 1) * 4;
    ushort4 pw;
    pw.x = f2bf(sa[ct][0] * inv); pw.y = f2bf(sa[ct][1] * inv);
    pw.z = f2bf(sa[ct][2] * inv); pw.w = f2bf(sa[ct][3] * inv);
    *(ushort4*)p = pw;
  }
  __syncthreads();

  f32x4 acc[5];
#pragma unroll
  for (int nf = 0; nf < 5; ++nf) acc[nf] = (f32x4){0.f, 0.f, 0.f, 0.f};
  const unsigned short* Vg = VcatT + (size_t)h * 80 * NTOK + m0;
#pragma unroll
  for (int kk = 0; kk < 8; ++kk) {
    int row = w * 16 + lr;
    int sl = (kk * 4 + lc) ^ (row & 7);
    bf16x8 a = *(const bf16x8*)(Ls + row * 256 + sl * 8);
#pragma unroll
    for (int nf = 0; nf < 5; ++nf) {
      int c = nf * 16 + lr;
      bf16x8 b = *(const bf16x8*)(Vg + (size_t)c * NTOK + kk * 32 + lc * 8);
      acc[nf] = __builtin_amdgcn_mfma_f32_16x16x32_bf16(a, b, acc[nf], 0, 0, 0);
    }
  }
  float* outz = acc4 + (size_t)blockIdx.y * SLA;
#pragma unroll
  for (int nf = 0; nf < 4; ++nf)
#pragma unroll
    for (int r = 0; r < 4; ++r) {
      int orow = n0 + w * 16 + lc * 4 + r;
      outz[(size_t)orow * 912 + h * 64 + nf * 16 + lr] = acc[nf][r];
    }
  if (lr < 12)
#pragma unroll
    for (int r = 0; r < 4; ++r) {
      int orow = n0 + w * 16 + lc * 4 + r;
      outz[(size_t)orow * 912 + 768 + h * 12 + lr] = acc[4][r];
    }
}

// ---------------------------------------------------------------------------
// tail gemm (k-split 8): A = bf16(sum of 4 f32 slabs) staged in-register.
// outpre[z] = A @ WB^T
// ---------------------------------------------------------------------------
__global__ __launch_bounds__(256) void tail_k(
    const float* __restrict__ acc4, const unsigned short* __restrict__ WB,
    float* __restrict__ outpre)
{
  __shared__ unsigned short As[128 * 32];
  __shared__ unsigned short Bs[128 * 32];
  const int t = threadIdx.x, w = t >> 6, lane = t & 63;
  const int wr = w >> 1, wc = w & 1;
  const int lr = lane & 15, lc = lane >> 4;
  const int m0 = blockIdx.x * 128, n0 = blockIdx.y * 128;
  const int z = blockIdx.z;
  const int kt0 = (z * 29) >> 3, kt1 = ((z + 1) * 29) >> 3;
  const int r0 = t >> 2, c0 = t & 3, r1 = r0 + 64;

  f32x4 acc[4][4] = {};
  u32x4 zz = {0u, 0u, 0u, 0u};
  bf16x8 zb = {0, 0, 0, 0, 0, 0, 0, 0};
  bf16x8 pa0, pa1; u32x4 pq0, pq1;

#define LOAD_T(KT)                                                               \
  do {                                                                           \
    int g0_ = (KT) * 32 + c0 * 8;                                                \
    pa0 = (g0_ < 912) ? sum4pack(acc4 + (size_t)(m0 + r0) * 912 + g0_) : zb;     \
    pa1 = (g0_ < 912) ? sum4pack(acc4 + (size_t)(m0 + r1) * 912 + g0_) : zb;     \
    pq0 = (g0_ < 912) ? *(const u32x4*)(WB + (size_t)(n0 + r0) * 912 + g0_) : zz; \
    pq1 = (g0_ < 912) ? *(const u32x4*)(WB + (size_t)(n0 + r1) * 912 + g0_) : zz; \
  } while (0)

  LOAD_T(kt0);
  for (int kt = kt0; kt < kt1; ++kt) {
    __syncthreads();
    *(bf16x8*)(As + (r0 * 4 + c0) * 8) = pa0;
    *(bf16x8*)(As + (r1 * 4 + c0) * 8) = pa1;
    ((u32x4*)Bs)[r0 * 4 + c0] = pq0;
    ((u32x4*)Bs)[r1 * 4 + c0] = pq1;
    __syncthreads();
    if (kt + 1 < kt1) LOAD_T(kt + 1);

    bf16x8 af[4], bfr[4];
#pragma unroll
    for (int mi = 0; mi < 4; ++mi) {
      int row = wr * 64 + mi * 16 + lr;
      af[mi] = *(const bf16x8*)(As + (row * 4 + lc) * 8);
    }
#pragma unroll
    for (int ni = 0; ni < 4; ++ni) {
      int row = wc * 64 + ni * 16 + lr;
      bfr[ni] = *(const bf16x8*)(Bs + (row * 4 + lc) * 8);
    }
#pragma unroll
    for (int mi = 0; mi < 4; ++mi)
#pragma unroll
      for (int ni = 0; ni < 4; ++ni)
        acc[mi][ni] = __builtin_amdgcn_mfma_f32_16x16x32_bf16(
            af[mi], bfr[ni], acc[mi][ni], 0, 0, 0);
  }
#undef LOAD_T

  float* outz = outpre + (size_t)z * 786432;
#pragma unroll
  for (int mi = 0; mi < 4; ++mi)
#pragma unroll
    for (int ni = 0; ni < 4; ++ni)
#pragma unroll
      for (int r = 0; r < 4; ++r) {
        int row = m0 + wr * 64 + mi * 16 + lc * 4 + r;
        int col = n0 + wc * 64 + ni * 16 + lr;
        outz[(size_t)row * 768 + col] = acc[mi][ni][r];
      }
}

// ---------------------------------------------------------------------------
// layernorm(single + sum(8 outpre slabs) + bfused) -> d_out
// ---------------------------------------------------------------------------
__global__ __launch_bounds__(256) void ln_k(
    const float* __restrict__ single, const float* __restrict__ outpre,
    const float* __restrict__ bfused, const float* __restrict__ g,
    const float* __restrict__ b, float* __restrict__ out)
{
  const int row = blockIdx.x, t = threadIdx.x;
  __shared__ float red[8];
  size_t base = (size_t)row * 768;
  const size_t SL = 786432;
  float x[3];
#pragma unroll
  for (int j = 0; j < 3; ++j) {
    int c = t + j * 256;
    float v = single[base + c] + bfused[c];
#pragma unroll
    for (int z = 0; z < 8; ++z) v += outpre[base + c + (size_t)z * SL];
    x[j] = v;
  }
  float s = x[0] + x[1] + x[2];
#pragma unroll
  for (int off = 32; off; off >>= 1) s += __shfl_xor(s, off, 64);
  if ((t & 63) == 0) red[t >> 6] = s;
  __syncthreads();
  float mu = (red[0] + red[1] + red[2] + red[3]) * (1.0f / 768.0f);
  float d0 = x[0] - mu, d1 = x[1] - mu, d2 = x[2] - mu;
  float vs = d0 * d0 + d1 * d1 + d2 * d2;
#pragma unroll
  for (int off = 32; off; off >>= 1) vs += __shfl_xor(vs, off, 64);
  if ((t & 63) == 0) red[4 + (t >> 6)] = vs;
  __syncthreads();
  float var = (red[4] + red[5] + red[6] + red[7]) * (1.0f / 768.0f);
  float rs = rsqrtf(var + 1e-5f);
  out[base + t]       = d0 * rs * g[t]       + b[t];
  out[base + t + 256] = d1 * rs * g[t + 256] + b[t + 256];
  out[base + t + 512] = d2 * rs * g[t + 512] + b[t + 512];
}

// ---------------------------------------------------------------------------
extern "C" void kernel_launch(void* const* d_in, const int* in_sizes, int n_in,
                              void* d_out, int out_size, void* d_ws, size_t ws_size,
                              hipStream_t stream)
{
  (void)in_sizes; (void)n_in; (void)out_size; (void)ws_size;
  const float* single = (const float*)d_in[0];
  const float* pair   = (const float*)d_in[1];
  const float* rot    = (const float*)d_in[2];
  const float* trans  = (const float*)d_in[3];
  const float* Wq  = (const float*)d_in[4];  const float* bq  = (const float*)d_in[5];
  const float* Wk  = (const float*)d_in[6];  const float* bk  = (const float*)d_in[7];
  const float* Wv  = (const float*)d_in[8];  const float* bv  = (const float*)d_in[9];
  const float* Wpb = (const float*)d_in[10]; const float* bpb = (const float*)d_in[11];
  const float* Wqp = (const float*)d_in[12]; const float* bqp = (const float*)d_in[13];
  const float* Wkp = (const float*)d_in[14]; const float* bkp = (const float*)d_in[15];
  const float* Wvp = (const float*)d_in[16]; const float* bvp = (const float*)d_in[17];
  const float* Wo  = (const float*)d_in[18]; const float* bo  = (const float*)d_in[19];
  const float* Wpo = (const float*)d_in[20]; const float* bpo = (const float*)d_in[21];
  const float* lng = (const float*)d_in[22]; const float* lnb = (const float*)d_in[23];

  char* ws = (char*)d_ws;
  unsigned short* sgl    = (unsigned short*)(ws + 0);
  unsigned short* wcat   = (unsigned short*)(ws + 1572864);
  unsigned short* wpoA   = (unsigned short*)(ws + 5775360);
  unsigned short* WB     = (unsigned short*)(ws + 5996544);
  float*          bcat   = (float*)(ws + 7397376);
  unsigned short* wpbt   = (unsigned short*)(ws + 7408320);
  float*          bfused = (float*)(ws + 7410432);
  float*          qp2    = (float*)(ws + 7413504);
  unsigned short* Acat   = (unsigned short*)(ws + 29826816);
  unsigned short* Bcat   = (unsigned short*)(ws + 32186112);
  unsigned short* VcatT  = (unsigned short*)(ws + 34545408);
  float*          q2k2   = (float*)(ws + 36511488);
  unsigned short* pb     = (unsigned short*)(ws + 36609792);
  float*          acc4   = (float*)(ws + 61775616);   // [4][1024][912] f32
  float*          outpre = (float*)(ws + 76717824);   // [8][1024][768] f32

  prep_k<<<3519, 256, 0, stream>>>(single, Wq, Wk, Wv, Wqp, Wkp, Wvp, Wpo, Wo,
                                   Wpb, bq, bk, bv, bqp, bkp, bvp,
                                   sgl, wcat, WB, wpoA, bcat, wpbt);

  projfat_k<<<367, 256, 0, stream>>>(sgl, wcat, bcat, qp2, wpoA, WB,
                                     bpo, Wo, bo, bfused);

  pairbias_k<<<4096, 256, 0, stream>>>(pair, wpbt, bpb, pb);

  rotate_k<<<1024, 256, 0, stream>>>(qp2, rot, trans, Acat, Bcat, VcatT, q2k2);

  attn_k<<<dim3(16, 4, 12), 256, 0, stream>>>(pb, Acat, Bcat, VcatT, q2k2, acc4);

  tail_k<<<dim3(8, 6, 8), 256, 0, stream>>>(acc4, WB, outpre);

  ln_k<<<1024, 256, 0, stream>>>(single, outpre, bfused, lng, lnb, (float*)d_out);
}

// Round 7
// 192.072 us; speedup vs baseline: 1.7889x; 1.0326x over previous
//
#include <hip/hip_runtime.h>
#include <hip/hip_bf16.h>
#include <stdint.h>

#define NTOK 1024
#define NH 12
#define QPSLAB 2801664   // 1024*2736

typedef short bf16x8 __attribute__((ext_vector_type(8)));
typedef float f32x4 __attribute__((ext_vector_type(4)));
typedef uint32_t u32x4 __attribute__((ext_vector_type(4)));

__device__ __forceinline__ unsigned short f2bf(float f) {
  union { float f; uint32_t u; } x; x.f = f;
  uint32_t r = x.u + 0x7FFFu + ((x.u >> 16) & 1u);
  return (unsigned short)(r >> 16);
}
__device__ __forceinline__ float bf2f(unsigned short u) {
  union { uint32_t u; float f; } x; x.u = ((uint32_t)u) << 16;
  return x.f;
}
// HW round-to-nearest-even pack: 8 f32 -> 8 bf16 (v_cvt_pk_bf16_f32)
__device__ __forceinline__ bf16x8 pack8(float4 a, float4 b) {
  union { __hip_bfloat162 h2[4]; bf16x8 v; } u;
  u.h2[0] = __float22bfloat162_rn(make_float2(a.x, a.y));
  u.h2[1] = __float22bfloat162_rn(make_float2(a.z, a.w));
  u.h2[2] = __float22bfloat162_rn(make_float2(b.x, b.y));
  u.h2[3] = __float22bfloat162_rn(make_float2(b.z, b.w));
  return u.v;
}

// ---------------------------------------------------------------------------
// prep: LDS-tiled transposes (coalesced both sides) + vectorized copies.
// ---------------------------------------------------------------------------
__global__ __launch_bounds__(256) void prep_k(
    const float* __restrict__ single, const float* __restrict__ Wq,
    const float* __restrict__ Wk, const float* __restrict__ Wv,
    const float* __restrict__ Wqp, const float* __restrict__ Wkp,
    const float* __restrict__ Wvp, const float* __restrict__ Wpo,
    const float* __restrict__ Wo, const float* __restrict__ Wpb,
    const float* __restrict__ bq, const float* __restrict__ bk,
    const float* __restrict__ bv, const float* __restrict__ bqp,
    const float* __restrict__ bkp, const float* __restrict__ bvp,
    unsigned short* __restrict__ sgl, unsigned short* __restrict__ wcat,
    unsigned short* __restrict__ WB, unsigned short* __restrict__ wpoA,
    float* __restrict__ bcat, unsigned short* __restrict__ wpbt)
{
  const int bid = blockIdx.x, t = threadIdx.x;
  if (bid < 2628) {
    __shared__ unsigned short tl[16][72];
    int b = bid;
    const float* src; unsigned short* dst; int N, dstld, rowbase;
    if (b < 1728) {
      int j = b / 576; b -= j * 576;
      src = (j == 0) ? Wq : (j == 1) ? Wk : Wv;
      N = 768; dst = wcat; dstld = 768; rowbase = j * 768;
    } else if (b < 2052) {
      b -= 1728; int j = b / 108; b -= j * 108;
      src = (j == 0) ? Wqp : (j == 1) ? Wkp : Wvp;
      N = 144; dst = wcat; dstld = 768; rowbase = 2304 + j * 144;
    } else {
      b -= 2052; src = Wo; N = 768; dst = WB; dstld = 912; rowbase = 0;
    }
    const int k0 = (b % 12) * 64, n0 = (b / 12) * 16;
#pragma unroll
    for (int i = 0; i < 4; ++i) {
      int kk = (t >> 4) + i * 16;
      int nn = t & 15;
      tl[nn][kk] = f2bf(src[(size_t)(k0 + kk) * N + n0 + nn]);
    }
    __syncthreads();
#pragma unroll
    for (int i = 0; i < 4; ++i) {
      int kk = t & 63;
      int nn = (t >> 6) + i * 4;
      dst[(size_t)(rowbase + n0 + nn) * dstld + k0 + kk] = tl[nn][kk];
    }
    return;
  }
  if (bid < 3396) {           // sgl float4 copy
    int i = (bid - 2628) * 256 + t;
    float4 v = *(const float4*)(single + (size_t)i * 4);
    ushort4 o;
    o.x = f2bf(v.x); o.y = f2bf(v.y); o.z = f2bf(v.z); o.w = f2bf(v.w);
    *(ushort4*)(sgl + (size_t)i * 4) = o;
    return;
  }
  if (bid < 3504) {           // wpoA straight copy
    int i = (bid - 3396) * 256 + t;
    float4 v = *(const float4*)(Wpo + (size_t)i * 4);
    ushort4 o;
    o.x = f2bf(v.x); o.y = f2bf(v.y); o.z = f2bf(v.z); o.w = f2bf(v.w);
    *(ushort4*)(wpoA + (size_t)i * 4) = o;
    return;
  }
  if (bid < 3515) {           // bcat
    int idx = (bid - 3504) * 256 + t;
    if (idx < 2736) {
      float v;
      if (idx < 768) v = bq[idx];
      else if (idx < 1536) v = bk[idx - 768];
      else if (idx < 2304) v = bv[idx - 1536];
      else if (idx < 2448) v = bqp[idx - 2304];
      else if (idx < 2592) v = bkp[idx - 2448];
      else v = bvp[idx - 2592];
      bcat[idx] = v;
    }
    return;
  }
  {                           // wpbt [16][64]
    int idx = (bid - 3515) * 256 + t;
    int h = idx >> 6, k = idx & 63;
    wpbt[idx] = (h < 12) ? f2bf(Wpb[k * 12 + h]) : (unsigned short)0;
  }
}

// ---------------------------------------------------------------------------
// shared MFMA GEMM body (bf16 A/B), 128x128 tile, BK=32.
// EPI 0: outf = v (+ p0[col]) ; EPI 1: outb[col*912+768+row] = bf16(v)
// ---------------------------------------------------------------------------
template <int EPI>
__device__ __forceinline__ void gemm_dev(
    unsigned short* As, unsigned short* Bs,
    const unsigned short* __restrict__ A, int lda, int Mact,
    const unsigned short* __restrict__ Bt, int ldb, int Nact,
    int kt0, int ktn, int kmax,
    float* __restrict__ outf, unsigned short* __restrict__ outb, int ldc,
    const float* __restrict__ p0, int mb, int nb, int addbias)
{
  const int t = threadIdx.x;
  const int w = t >> 6, lane = t & 63;
  const int wr = w >> 1, wc = w & 1;
  const int lr = lane & 15, lc = lane >> 4;
  const int m0 = mb * 128, n0 = nb * 128;
  const int r0 = t >> 2, c0 = t & 3;
  const int r1 = r0 + 64;

  f32x4 acc[4][4] = {};
  u32x4 zz = {0u, 0u, 0u, 0u};
  u32x4 pa0, pa1, pq0, pq1;

#define LOAD_AB(KT)                                                              \
  do {                                                                           \
    int k0_ = (KT) * 32;                                                         \
    int g0_ = k0_ + c0 * 8;                                                      \
    pa0 = (g0_ < kmax && (m0 + r0) < Mact)                                       \
              ? *(const u32x4*)(A + (size_t)(m0 + r0) * lda + g0_) : zz;         \
    pa1 = (g0_ < kmax && (m0 + r1) < Mact)                                       \
              ? *(const u32x4*)(A + (size_t)(m0 + r1) * lda + g0_) : zz;         \
    pq0 = (g0_ < kmax && (n0 + r0) < Nact)                                       \
              ? *(const u32x4*)(Bt + (size_t)(n0 + r0) * ldb + g0_) : zz;        \
    pq1 = (g0_ < kmax && (n0 + r1) < Nact)                                       \
              ? *(const u32x4*)(Bt + (size_t)(n0 + r1) * ldb + g0_) : zz;        \
  } while (0)

  LOAD_AB(kt0);
  for (int kt = kt0; kt < kt0 + ktn; ++kt) {
    __syncthreads();
    ((u32x4*)As)[r0 * 4 + c0] = pa0;
    ((u32x4*)As)[r1 * 4 + c0] = pa1;
    ((u32x4*)Bs)[r0 * 4 + c0] = pq0;
    ((u32x4*)Bs)[r1 * 4 + c0] = pq1;
    __syncthreads();
    if (kt + 1 < kt0 + ktn) LOAD_AB(kt + 1);

    bf16x8 af[4], bfr[4];
#pragma unroll
    for (int mi = 0; mi < 4; ++mi) {
      int row = wr * 64 + mi * 16 + lr;
      af[mi] = *(const bf16x8*)(As + (row * 4 + lc) * 8);
    }
#pragma unroll
    for (int ni = 0; ni < 4; ++ni) {
      int row = wc * 64 + ni * 16 + lr;
      bfr[ni] = *(const bf16x8*)(Bs + (row * 4 + lc) * 8);
    }
#pragma unroll
    for (int mi = 0; mi < 4; ++mi)
#pragma unroll
      for (int ni = 0; ni < 4; ++ni)
        acc[mi][ni] = __builtin_amdgcn_mfma_f32_16x16x32_bf16(
            af[mi], bfr[ni], acc[mi][ni], 0, 0, 0);
  }
#undef LOAD_AB

#pragma unroll
  for (int mi = 0; mi < 4; ++mi) {
#pragma unroll
    for (int ni = 0; ni < 4; ++ni) {
#pragma unroll
      for (int r = 0; r < 4; ++r) {
        int row = m0 + wr * 64 + mi * 16 + lc * 4 + r;
        int col = n0 + wc * 64 + ni * 16 + lr;
        if (row < Mact && col < Nact) {
          float v = acc[mi][ni][r];
          if constexpr (EPI == 0) {
            outf[(size_t)row * ldc + col] = addbias ? (v + p0[col]) : v;
          } else {
            outb[(size_t)col * 912 + 768 + row] = f2bf(v);
          }
        }
      }
    }
  }
}

// ---------------------------------------------------------------------------
// fat kernel: [0..4095] pairbias (FIRST: starts 256MB stream at t=0)
// [4096..4107] wfuse  [4108..4110] bfused  [4111..4462] proj(ks2)
// pairbias: 2-deep prefetch + HW cvt_pk pack.
// ---------------------------------------------------------------------------
__global__ __launch_bounds__(256) void fat_k(
    const unsigned short* __restrict__ sgl, const unsigned short* __restrict__ wcat,
    const float* __restrict__ bcat, float* __restrict__ qp2,
    const float* __restrict__ pair, const unsigned short* __restrict__ wpbt,
    const float* __restrict__ bpb, unsigned short* __restrict__ pb,
    const unsigned short* __restrict__ wpoA, unsigned short* __restrict__ WB,
    const float* __restrict__ bpo, const float* __restrict__ Wo,
    const float* __restrict__ bo, float* __restrict__ bfused)
{
  const int bid = blockIdx.x;
  const int t = threadIdx.x;

  if (bid < 4096) {           // pairbias
    const int w = t >> 6, lane = t & 63;
    const int lr = lane & 15, g = lane >> 4;
    bf16x8 wf0 = *(const bf16x8*)(wpbt + lr * 64 + g * 8);
    bf16x8 wf1 = *(const bf16x8*)(wpbt + lr * 64 + 32 + g * 8);
    const float bias_h = (lr < 12) ? bpb[lr] : 0.f;
    const int wid = bid * 4 + w;
    const float* s = pair + ((size_t)(wid * 64) + lr) * 64 + g * 8;
    float4 nA = *(const float4*)(s);
    float4 nB = *(const float4*)(s + 4);
    float4 nC = *(const float4*)(s + 32);
    float4 nD = *(const float4*)(s + 36);
#pragma unroll
    for (int it = 0; it < 4; ++it) {
      float4 aA = nA, aB = nB, aC = nC, aD = nD;
      if (it < 3) {                      // issue next tile's loads early
        const float* p = s + (size_t)(it + 1) * 1024;
        nA = *(const float4*)(p);
        nB = *(const float4*)(p + 4);
        nC = *(const float4*)(p + 32);
        nD = *(const float4*)(p + 36);
      }
      bf16x8 f0 = pack8(aA, aB);
      bf16x8 f1 = pack8(aC, aD);
      f32x4 c = {0.f, 0.f, 0.f, 0.f};
      c = __builtin_amdgcn_mfma_f32_16x16x32_bf16(f0, wf0, c, 0, 0, 0);
      c = __builtin_amdgcn_mfma_f32_16x16x32_bf16(f1, wf1, c, 0, 0, 0);
      if (lr < 12) {
        int nm0 = (wid * 4 + it) * 16;
        union { __hip_bfloat162 h2[2]; ushort4 s4; } pu;
        pu.h2[0] = __float22bfloat162_rn(make_float2(c[0] + bias_h, c[1] + bias_h));
        pu.h2[1] = __float22bfloat162_rn(make_float2(c[2] + bias_h, c[3] + bias_h));
        *(ushort4*)(pb + ((size_t)lr << 20) + (size_t)nm0 + g * 4) = pu.s4;
      }
    }
    return;
  }

  __shared__ unsigned short As[128 * 32];
  __shared__ unsigned short Bs[128 * 32];
  int rb = bid - 4096;
  if (rb < 12) {              // wfuse: Wfused = Wpo @ Wo -> WB[:,768:912]
    int mb = rb & 1, nb = rb >> 1;
    gemm_dev<1>(As, Bs, wpoA, 768, 144, WB, 912, 768, 0, 24, 768,
                nullptr, WB, 912, nullptr, mb, nb, 0);
    return;
  }
  if (rb < 15) {              // bfused[n] = bpo @ Wo + bo
    int n = (rb - 12) * 256 + t;
    float sacc = bo[n];
    for (int j = 0; j < 768; ++j) sacc += bpo[j] * Wo[(size_t)j * 768 + n];
    bfused[n] = sacc;
    return;
  }
  {                           // proj, k-split 2
    int pbid = rb - 15;
    int zk = pbid / 176, rem = pbid % 176;
    int mb = rem & 7, nb = rem >> 3;
    gemm_dev<0>(As, Bs, sgl, 768, 1024, wcat, 768, 2736,
                zk * 12, 12, 768,
                qp2 + (size_t)zk * QPSLAB, nullptr, 2736, bcat, mb, nb, zk == 0);
  }
}

// ---------------------------------------------------------------------------
// rotate
// ---------------------------------------------------------------------------
__global__ __launch_bounds__(256) void rotate_k(
    const float* __restrict__ qp2, const float* __restrict__ rot,
    const float* __restrict__ trans,
    unsigned short* __restrict__ Acat, unsigned short* __restrict__ Bcat,
    unsigned short* __restrict__ VcatT, float* __restrict__ q2k2)
{
  const int n = blockIdx.x, t = threadIdx.x;
  __shared__ float R[9], T[3], rg[432];
  if (t < 9) R[t] = rot[n * 9 + t];
  if (t >= 9 && t < 12) T[t - 9] = trans[n * 3 + (t - 9)];
  __syncthreads();
  for (int s = t; s < 432; s += 256) {
    int j = s / 144, r = s % 144;
    int h = r / 12, wo = r % 12;
    int e = wo % 3;
    size_t base = (size_t)n * 2736 + 2304 + j * 144 + (r - e);
    float d0 = qp2[base + 0] + qp2[base + 0 + QPSLAB];
    float d1 = qp2[base + 1] + qp2[base + 1 + QPSLAB];
    float d2 = qp2[base + 2] + qp2[base + 2 + QPSLAB];
    float val = d0 * R[e] + d1 * R[3 + e] + d2 * R[6 + e] + T[e];
    rg[s] = val;
    unsigned short bv = f2bf(val);
    if (j == 0)      Acat[((size_t)h * NTOK + n) * 96 + 64 + wo] = bv;
    else if (j == 1) Bcat[((size_t)h * NTOK + n) * 96 + 64 + wo] = bv;
    else             VcatT[((size_t)h * 80 + 64 + wo) * NTOK + n] = bv;
  }
  __syncthreads();
  for (int s = t; s < 2304; s += 256) {
    int j = s / 768, c = s % 768;
    int h = c >> 6, cc = c & 63;
    size_t ix = (size_t)n * 2736 + s;
    unsigned short bv = f2bf(qp2[ix] + qp2[ix + QPSLAB]);
    if (j == 0)      Acat[((size_t)h * NTOK + n) * 96 + cc] = bv;
    else if (j == 1) Bcat[((size_t)h * NTOK + n) * 96 + cc] = bv;
    else             VcatT[((size_t)h * 80 + cc) * NTOK + n] = bv;
  }
  if (t < 240) {
    int h = t / 20, ix = 76 + t % 20;
    Acat[((size_t)h * NTOK + n) * 96 + ix] = 0;
    Bcat[((size_t)h * NTOK + n) * 96 + ix] = 0;
  }
  if (t >= 240 && t < 288) {
    int s = t - 240;
    int h = s / 4, rr = 76 + s % 4;
    VcatT[((size_t)h * 80 + rr) * NTOK + n] = 0;
  }
  if (t < 24) {
    int j = t / 12, h = t % 12;
    float sum = 0.f;
#pragma unroll
    for (int wo = 0; wo < 12; ++wo) {
      float v = rg[j * 144 + h * 12 + wo];
      sum += v * v;
    }
    q2k2[(size_t)(j * NH + h) * NTOK + n] = sum;
  }
}

// ---------------------------------------------------------------------------
// fused attention (round-4 structure; cvt_pk P-write)
// ---------------------------------------------------------------------------
__global__ __launch_bounds__(256) void attn_k(
    const unsigned short* __restrict__ pb, const unsigned short* __restrict__ Acat,
    const unsigned short* __restrict__ Bcat, const unsigned short* __restrict__ VcatT,
    const float* __restrict__ q2k2, float* __restrict__ acc4)
{
  __shared__ unsigned short Ls[64 * 256];
  __shared__ unsigned short Bs[128 * 104];
  const int t = threadIdx.x, w = t >> 6, lane = t & 63;
  const int lr = lane & 15, lc = lane >> 4;
  const int n0 = blockIdx.x * 64;
  const int m0 = blockIdx.y * 256;
  const int h  = blockIdx.z;

  const unsigned short* Pg = pb + ((size_t)h << 20) + (size_t)n0 * 1024 + m0;
#pragma unroll
  for (int i = 0; i < 8; ++i) {
    int idx = i * 256 + t;
    int row = idx >> 5, sl = idx & 31;
    u32x4 v = *(const u32x4*)(Pg + (size_t)row * 1024 + sl * 8);
    ((u32x4*)Ls)[row * 32 + (sl ^ (row & 7))] = v;
  }
  const unsigned short* Kg = Bcat + ((size_t)h * 1024 + m0) * 96;
#pragma unroll
  for (int i = 0; i < 6; ++i) {
    int idx = i * 256 + t;
    int row = idx / 12, c = idx % 12;
    u32x4 v = *(const u32x4*)(Kg + (size_t)row * 96 + c * 8);
    *(u32x4*)(Bs + row * 104 + c * 8) = v;
  }
  __syncthreads();

  bf16x8 qf[3];
  const unsigned short* Qg = Acat + ((size_t)h * 1024 + n0 + w * 16 + lr) * 96;
#pragma unroll
  for (int kk = 0; kk < 3; ++kk) qf[kk] = *(const bf16x8*)(Qg + kk * 32 + lc * 8);

  f32x4 sa[16];
#pragma unroll
  for (int ct = 0; ct < 16; ++ct) sa[ct] = (f32x4){0.f, 0.f, 0.f, 0.f};

#pragma unroll
  for (int ct = 0; ct < 8; ++ct)
#pragma unroll
    for (int kk = 0; kk < 3; ++kk) {
      bf16x8 kf = *(const bf16x8*)(Bs + (ct * 16 + lr) * 104 + kk * 32 + lc * 8);
      sa[ct] = __builtin_amdgcn_mfma_f32_16x16x32_bf16(kf, qf[kk], sa[ct], 0, 0, 0);
    }
  __syncthreads();
#pragma unroll
  for (int i = 0; i < 6; ++i) {
    int idx = i * 256 + t;
    int row = idx / 12, c = idx % 12;
    u32x4 v = *(const u32x4*)(Kg + (size_t)(128 + row) * 96 + c * 8);
    *(u32x4*)(Bs + row * 104 + c * 8) = v;
  }
  __syncthreads();
#pragma unroll
  for (int ct = 8; ct < 16; ++ct)
#pragma unroll
    for (int kk = 0; kk < 3; ++kk) {
      bf16x8 kf = *(const bf16x8*)(Bs + ((ct - 8) * 16 + lr) * 104 + kk * 32 + lc * 8);
      sa[ct] = __builtin_amdgcn_mfma_f32_16x16x32_bf16(kf, qf[kk], sa[ct], 0, 0, 0);
    }

  const int nrow = w * 16 + lr;
  const float q2v = q2k2[(size_t)h * 1024 + n0 + nrow];
  const float* k2b = q2k2 + 12288 + (size_t)h * 1024 + m0;
  float mx = -1e30f;
#pragma unroll
  for (int ct = 0; ct < 16; ++ct) {
    int sl = (ct * 2 + (lc >> 1)) ^ (nrow & 7);
    const unsigned short* p = Ls + nrow * 256 + sl * 8 + (lc & 1) * 4;
    ushort4 pv = *(const ushort4*)p;
    float4 k2v = *(const float4*)(k2b + ct * 16 + lc * 4);
    sa[ct][0] = 0.125f * sa[ct][0] + bf2f(pv.x) - 0.0625f * (q2v + k2v.x);
    sa[ct][1] = 0.125f * sa[ct][1] + bf2f(pv.y) - 0.0625f * (q2v + k2v.y);
    sa[ct][2] = 0.125f * sa[ct][2] + bf2f(pv.z) - 0.0625f * (q2v + k2v.z);
    sa[ct][3] = 0.125f * sa[ct][3] + bf2f(pv.w) - 0.0625f * (q2v + k2v.w);
    mx = fmaxf(mx, fmaxf(fmaxf(sa[ct][0], sa[ct][1]), fmaxf(sa[ct][2], sa[ct][3])));
  }
  mx = fmaxf(mx, __shfl_xor(mx, 16, 64));
  mx = fmaxf(mx, __shfl_xor(mx, 32, 64));
  float sm = 0.f;
#pragma unroll
  for (int ct = 0; ct < 16; ++ct)
#pragma unroll
    for (int r = 0; r < 4; ++r) { sa[ct][r] = __expf(sa[ct][r] - mx); sm += sa[ct][r]; }
  sm += __shfl_xor(sm, 16, 64);
  sm += __shfl_xor(sm, 32, 64);
  float inv = 1.0f / sm;
#pragma unroll
  for (int ct = 0; ct < 16; ++ct) {
    int sl = (ct * 2 + (lc >> 1)) ^ (nrow & 7);
    unsigned short* p = Ls + nrow * 256 + sl * 8 + (lc & 1) * 4;
    union { __hip_bfloat162 h2[2]; ushort4 s4; } pu;
    pu.h2[0] = __float22bfloat162_rn(make_float2(sa[ct][0] * inv, sa[ct][1] * inv));
    pu.h2[1] = __float22bfloat162_rn(make_float2(sa[ct][2] * inv, sa[ct][3] * inv));
    *(ushort4*)p = pu.s4;
  }
  __syncthreads();

  f32x4 acc[5];
#pragma unroll
  for (int nf = 0; nf < 5; ++nf) acc[nf] = (f32x4){0.f, 0.f, 0.f, 0.f};
  const unsigned short* Vg = VcatT + (size_t)h * 80 * NTOK + m0;
#pragma unroll
  for (int kk = 0; kk < 8; ++kk) {
    int row = w * 16 + lr;
    int sl = (kk * 4 + lc) ^ (row & 7);
    bf16x8 a = *(const bf16x8*)(Ls + row * 256 + sl * 8);
#pragma unroll
    for (int nf = 0; nf < 5; ++nf) {
      int c = nf * 16 + lr;
      bf16x8 b = *(const bf16x8*)(Vg + (size_t)c * NTOK + kk * 32 + lc * 8);
      acc[nf] = __builtin_amdgcn_mfma_f32_16x16x32_bf16(a, b, acc[nf], 0, 0, 0);
    }
  }
  float* out = acc4 + ((size_t)blockIdx.y * NH + h) * (size_t)NTOK * 80;
#pragma unroll
  for (int nf = 0; nf < 5; ++nf)
#pragma unroll
    for (int r = 0; r < 4; ++r) {
      int orow = n0 + w * 16 + lc * 4 + r;
      int c = nf * 16 + lr;
      out[(size_t)orow * 80 + c] = acc[nf][r];
    }
}

// ---------------------------------------------------------------------------
// reduce 4 chunk slabs -> AW bf16 [1024][912] = [ws | wp]
// ---------------------------------------------------------------------------
__global__ __launch_bounds__(256) void reduce_k(
    const float* __restrict__ acc4, unsigned short* __restrict__ AW)
{
  int idx = blockIdx.x * 256 + threadIdx.x;
  if (idx >= 1024 * 912) return;
  int n = idx / 912, c = idx % 912;
  const size_t cs = (size_t)NH * NTOK * 80;
  size_t base;
  if (c < 768) {
    int h = c >> 6, cc = c & 63;
    base = ((size_t)h * NTOK + n) * 80 + cc;
  } else {
    int c2 = c - 768;
    int h = c2 / 12, wo = c2 % 12;
    base = ((size_t)h * NTOK + n) * 80 + 64 + wo;
  }
  float v = acc4[base] + acc4[base + cs] + acc4[base + 2 * cs] + acc4[base + 3 * cs];
  AW[(size_t)n * 912 + c] = f2bf(v);
}

// ---------------------------------------------------------------------------
// tail gemm (k-split 4): outpre[z] = AW @ WB^T
// ---------------------------------------------------------------------------
__global__ __launch_bounds__(256) void tail_gemm_k(
    const unsigned short* __restrict__ AW, const unsigned short* __restrict__ WB,
    float* __restrict__ outpre)
{
  __shared__ unsigned short As[128 * 32];
  __shared__ unsigned short Bs[128 * 32];
  int z = blockIdx.z;
  int kt0 = z * 8, ktn = (z < 3) ? 8 : 5;
  gemm_dev<0>(As, Bs, AW, 912, 1024, WB, 912, 768, kt0, ktn, 912,
              outpre + (size_t)z * 786432, nullptr, 768, nullptr,
              blockIdx.x, blockIdx.y, 0);
}

// ---------------------------------------------------------------------------
// layernorm(single + sum(4 outpre slabs) + bfused) -> d_out
// ---------------------------------------------------------------------------
__global__ __launch_bounds__(256) void ln_k(
    const float* __restrict__ single, const float* __restrict__ outpre,
    const float* __restrict__ bfused, const float* __restrict__ g,
    const float* __restrict__ b, float* __restrict__ out)
{
  const int row = blockIdx.x, t = threadIdx.x;
  __shared__ float red[8];
  size_t base = (size_t)row * 768;
  const size_t SL = 786432;
  float x[3];
#pragma unroll
  for (int j = 0; j < 3; ++j) {
    int c = t + j * 256;
    float v = single[base + c] + bfused[c];
#pragma unroll
    for (int z = 0; z < 4; ++z) v += outpre[base + c + (size_t)z * SL];
    x[j] = v;
  }
  float s = x[0] + x[1] + x[2];
#pragma unroll
  for (int off = 32; off; off >>= 1) s += __shfl_xor(s, off, 64);
  if ((t & 63) == 0) red[t >> 6] = s;
  __syncthreads();
  float mu = (red[0] + red[1] + red[2] + red[3]) * (1.0f / 768.0f);
  float d0 = x[0] - mu, d1 = x[1] - mu, d2 = x[2] - mu;
  float vs = d0 * d0 + d1 * d1 + d2 * d2;
#pragma unroll
  for (int off = 32; off; off >>= 1) vs += __shfl_xor(vs, off, 64);
  if ((t & 63) == 0) red[4 + (t >> 6)] = vs;
  __syncthreads();
  float var = (red[4] + red[5] + red[6] + red[7]) * (1.0f / 768.0f);
  float rs = rsqrtf(var + 1e-5f);
  out[base + t]       = d0 * rs * g[t]       + b[t];
  out[base + t + 256] = d1 * rs * g[t + 256] + b[t + 256];
  out[base + t + 512] = d2 * rs * g[t + 512] + b[t + 512];
}

// ---------------------------------------------------------------------------
extern "C" void kernel_launch(void* const* d_in, const int* in_sizes, int n_in,
                              void* d_out, int out_size, void* d_ws, size_t ws_size,
                              hipStream_t stream)
{
  (void)in_sizes; (void)n_in; (void)out_size; (void)ws_size;
  const float* single = (const float*)d_in[0];
  const float* pair   = (const float*)d_in[1];
  const float* rot    = (const float*)d_in[2];
  const float* trans  = (const float*)d_in[3];
  const float* Wq  = (const float*)d_in[4];  const float* bq  = (const float*)d_in[5];
  const float* Wk  = (const float*)d_in[6];  const float* bk  = (const float*)d_in[7];
  const float* Wv  = (const float*)d_in[8];  const float* bv  = (const float*)d_in[9];
  const float* Wpb = (const float*)d_in[10]; const float* bpb = (const float*)d_in[11];
  const float* Wqp = (const float*)d_in[12]; const float* bqp = (const float*)d_in[13];
  const float* Wkp = (const float*)d_in[14]; const float* bkp = (const float*)d_in[15];
  const float* Wvp = (const float*)d_in[16]; const float* bvp = (const float*)d_in[17];
  const float* Wo  = (const float*)d_in[18]; const float* bo  = (const float*)d_in[19];
  const float* Wpo = (const float*)d_in[20]; const float* bpo = (const float*)d_in[21];
  const float* lng = (const float*)d_in[22]; const float* lnb = (const float*)d_in[23];

  char* ws = (char*)d_ws;
  unsigned short* sgl    = (unsigned short*)(ws + 0);
  unsigned short* wcat   = (unsigned short*)(ws + 1572864);
  unsigned short* wpoA   = (unsigned short*)(ws + 5775360);
  unsigned short* WB     = (unsigned short*)(ws + 5996544);
  float*          bcat   = (float*)(ws + 7397376);
  unsigned short* wpbt   = (unsigned short*)(ws + 7408320);
  float*          bfused = (float*)(ws + 7410432);
  float*          qp2    = (float*)(ws + 7413504);
  unsigned short* Acat   = (unsigned short*)(ws + 29826816);
  unsigned short* Bcat   = (unsigned short*)(ws + 32186112);
  unsigned short* VcatT  = (unsigned short*)(ws + 34545408);
  float*          q2k2   = (float*)(ws + 36511488);
  unsigned short* pb     = (unsigned short*)(ws + 36609792);
  float*          acc4   = (float*)(ws + 61775616);   // [4][12*1024*80] f32
  unsigned short* AW     = (unsigned short*)(ws + 77504256);
  float*          outpre = (float*)(ws + 79372032);   // [4][1024][768] f32

  prep_k<<<3519, 256, 0, stream>>>(single, Wq, Wk, Wv, Wqp, Wkp, Wvp, Wpo, Wo,
                                   Wpb, bq, bk, bv, bqp, bkp, bvp,
                                   sgl, wcat, WB, wpoA, bcat, wpbt);

  fat_k<<<4463, 256, 0, stream>>>(sgl, wcat, bcat, qp2, pair, wpbt, bpb, pb,
                                  wpoA, WB, bpo, Wo, bo, bfused);

  rotate_k<<<1024, 256, 0, stream>>>(qp2, rot, trans, Acat, Bcat, VcatT, q2k2);

  attn_k<<<dim3(16, 4, 12), 256, 0, stream>>>(pb, Acat, Bcat, VcatT, q2k2, acc4);

  reduce_k<<<3648, 256, 0, stream>>>(acc4, AW);

  tail_gemm_k<<<dim3(8, 6, 4), 256, 0, stream>>>(AW, WB, outpre);

  ln_k<<<1024, 256, 0, stream>>>(single, outpre, bfused, lng, lnb, (float*)d_out);
}

// Round 8
// 166.181 us; speedup vs baseline: 2.0676x; 1.1558x over previous
//
#include <hip/hip_runtime.h>
#include <hip/hip_bf16.h>
#include <stdint.h>

#define NTOK 1024
#define NH 12
#define QPSLAB 2801664   // 1024*2736

typedef short bf16x8 __attribute__((ext_vector_type(8)));
typedef float f32x4 __attribute__((ext_vector_type(4)));
typedef uint32_t u32x4 __attribute__((ext_vector_type(4)));

__device__ __forceinline__ unsigned short f2bf(float f) {
  union { float f; uint32_t u; } x; x.f = f;
  uint32_t r = x.u + 0x7FFFu + ((x.u >> 16) & 1u);
  return (unsigned short)(r >> 16);
}
__device__ __forceinline__ float bf2f(unsigned short u) {
  union { uint32_t u; float f; } x; x.u = ((uint32_t)u) << 16;
  return x.f;
}

// ---------------------------------------------------------------------------
// prep: LDS-tiled transposes (coalesced both sides) + vectorized copies.
// ---------------------------------------------------------------------------
__global__ __launch_bounds__(256) void prep_k(
    const float* __restrict__ single, const float* __restrict__ Wq,
    const float* __restrict__ Wk, const float* __restrict__ Wv,
    const float* __restrict__ Wqp, const float* __restrict__ Wkp,
    const float* __restrict__ Wvp, const float* __restrict__ Wpo,
    const float* __restrict__ Wo, const float* __restrict__ Wpb,
    const float* __restrict__ bq, const float* __restrict__ bk,
    const float* __restrict__ bv, const float* __restrict__ bqp,
    const float* __restrict__ bkp, const float* __restrict__ bvp,
    unsigned short* __restrict__ sgl, unsigned short* __restrict__ wcat,
    unsigned short* __restrict__ WB, unsigned short* __restrict__ wpoA,
    float* __restrict__ bcat, unsigned short* __restrict__ wpbt)
{
  const int bid = blockIdx.x, t = threadIdx.x;
  if (bid < 2628) {
    __shared__ unsigned short tl[16][72];
    int b = bid;
    const float* src; unsigned short* dst; int N, dstld, rowbase;
    if (b < 1728) {
      int j = b / 576; b -= j * 576;
      src = (j == 0) ? Wq : (j == 1) ? Wk : Wv;
      N = 768; dst = wcat; dstld = 768; rowbase = j * 768;
    } else if (b < 2052) {
      b -= 1728; int j = b / 108; b -= j * 108;
      src = (j == 0) ? Wqp : (j == 1) ? Wkp : Wvp;
      N = 144; dst = wcat; dstld = 768; rowbase = 2304 + j * 144;
    } else {
      b -= 2052; src = Wo; N = 768; dst = WB; dstld = 912; rowbase = 0;
    }
    const int k0 = (b % 12) * 64, n0 = (b / 12) * 16;
#pragma unroll
    for (int i = 0; i < 4; ++i) {
      int kk = (t >> 4) + i * 16;
      int nn = t & 15;
      tl[nn][kk] = f2bf(src[(size_t)(k0 + kk) * N + n0 + nn]);
    }
    __syncthreads();
#pragma unroll
    for (int i = 0; i < 4; ++i) {
      int kk = t & 63;
      int nn = (t >> 6) + i * 4;
      dst[(size_t)(rowbase + n0 + nn) * dstld + k0 + kk] = tl[nn][kk];
    }
    return;
  }
  if (bid < 3396) {           // sgl float4 copy
    int i = (bid - 2628) * 256 + t;
    float4 v = *(const float4*)(single + (size_t)i * 4);
    ushort4 o;
    o.x = f2bf(v.x); o.y = f2bf(v.y); o.z = f2bf(v.z); o.w = f2bf(v.w);
    *(ushort4*)(sgl + (size_t)i * 4) = o;
    return;
  }
  if (bid < 3504) {           // wpoA straight copy
    int i = (bid - 3396) * 256 + t;
    float4 v = *(const float4*)(Wpo + (size_t)i * 4);
    ushort4 o;
    o.x = f2bf(v.x); o.y = f2bf(v.y); o.z = f2bf(v.z); o.w = f2bf(v.w);
    *(ushort4*)(wpoA + (size_t)i * 4) = o;
    return;
  }
  if (bid < 3515) {           // bcat
    int idx = (bid - 3504) * 256 + t;
    if (idx < 2736) {
      float v;
      if (idx < 768) v = bq[idx];
      else if (idx < 1536) v = bk[idx - 768];
      else if (idx < 2304) v = bv[idx - 1536];
      else if (idx < 2448) v = bqp[idx - 2304];
      else if (idx < 2592) v = bkp[idx - 2448];
      else v = bvp[idx - 2592];
      bcat[idx] = v;
    }
    return;
  }
  {                           // wpbt [16][64]
    int idx = (bid - 3515) * 256 + t;
    int h = idx >> 6, k = idx & 63;
    wpbt[idx] = (h < 12) ? f2bf(Wpb[k * 12 + h]) : (unsigned short)0;
  }
}

// ---------------------------------------------------------------------------
// shared MFMA GEMM body (bf16 A/B), 128x128 tile, BK=32.
// EPI 0: outf = v (+ p0[col]) ; EPI 1: outb[col*912+768+row] = bf16(v)
// ---------------------------------------------------------------------------
template <int EPI>
__device__ __forceinline__ void gemm_dev(
    unsigned short* As, unsigned short* Bs,
    const unsigned short* __restrict__ A, int lda, int Mact,
    const unsigned short* __restrict__ Bt, int ldb, int Nact,
    int kt0, int ktn, int kmax,
    float* __restrict__ outf, unsigned short* __restrict__ outb, int ldc,
    const float* __restrict__ p0, int mb, int nb, int addbias)
{
  const int t = threadIdx.x;
  const int w = t >> 6, lane = t & 63;
  const int wr = w >> 1, wc = w & 1;
  const int lr = lane & 15, lc = lane >> 4;
  const int m0 = mb * 128, n0 = nb * 128;
  const int r0 = t >> 2, c0 = t & 3;
  const int r1 = r0 + 64;

  f32x4 acc[4][4] = {};
  u32x4 zz = {0u, 0u, 0u, 0u};
  u32x4 pa0, pa1, pq0, pq1;

#define LOAD_AB(KT)                                                              \
  do {                                                                           \
    int k0_ = (KT) * 32;                                                         \
    int g0_ = k0_ + c0 * 8;                                                      \
    pa0 = (g0_ < kmax && (m0 + r0) < Mact)                                       \
              ? *(const u32x4*)(A + (size_t)(m0 + r0) * lda + g0_) : zz;         \
    pa1 = (g0_ < kmax && (m0 + r1) < Mact)                                       \
              ? *(const u32x4*)(A + (size_t)(m0 + r1) * lda + g0_) : zz;         \
    pq0 = (g0_ < kmax && (n0 + r0) < Nact)                                       \
              ? *(const u32x4*)(Bt + (size_t)(n0 + r0) * ldb + g0_) : zz;        \
    pq1 = (g0_ < kmax && (n0 + r1) < Nact)                                       \
              ? *(const u32x4*)(Bt + (size_t)(n0 + r1) * ldb + g0_) : zz;        \
  } while (0)

  LOAD_AB(kt0);
  for (int kt = kt0; kt < kt0 + ktn; ++kt) {
    __syncthreads();
    ((u32x4*)As)[r0 * 4 + c0] = pa0;
    ((u32x4*)As)[r1 * 4 + c0] = pa1;
    ((u32x4*)Bs)[r0 * 4 + c0] = pq0;
    ((u32x4*)Bs)[r1 * 4 + c0] = pq1;
    __syncthreads();
    if (kt + 1 < kt0 + ktn) LOAD_AB(kt + 1);

    bf16x8 af[4], bfr[4];
#pragma unroll
    for (int mi = 0; mi < 4; ++mi) {
      int row = wr * 64 + mi * 16 + lr;
      af[mi] = *(const bf16x8*)(As + (row * 4 + lc) * 8);
    }
#pragma unroll
    for (int ni = 0; ni < 4; ++ni) {
      int row = wc * 64 + ni * 16 + lr;
      bfr[ni] = *(const bf16x8*)(Bs + (row * 4 + lc) * 8);
    }
#pragma unroll
    for (int mi = 0; mi < 4; ++mi)
#pragma unroll
      for (int ni = 0; ni < 4; ++ni)
        acc[mi][ni] = __builtin_amdgcn_mfma_f32_16x16x32_bf16(
            af[mi], bfr[ni], acc[mi][ni], 0, 0, 0);
  }
#undef LOAD_AB

#pragma unroll
  for (int mi = 0; mi < 4; ++mi) {
#pragma unroll
    for (int ni = 0; ni < 4; ++ni) {
#pragma unroll
      for (int r = 0; r < 4; ++r) {
        int row = m0 + wr * 64 + mi * 16 + lc * 4 + r;
        int col = n0 + wc * 64 + ni * 16 + lr;
        if (row < Mact && col < Nact) {
          float v = acc[mi][ni][r];
          if constexpr (EPI == 0) {
            outf[(size_t)row * ldc + col] = addbias ? (v + p0[col]) : v;
          } else {
            outb[(size_t)col * 912 + 768 + row] = f2bf(v);
          }
        }
      }
    }
  }
}

// ---------------------------------------------------------------------------
// fat kernel (round-4 order): [0..11] wfuse  [12..14] bfused  [15..366]
// proj(ks2)  [367..4462] pairbias.
// pairbias NEW: coalesced 1KB loads -> cvt_pk -> wave-private LDS transpose
// (double-buffered, 1 barrier/iter) -> MFMA A-frag reads.
// ---------------------------------------------------------------------------
__global__ __launch_bounds__(256) void fat_k(
    const unsigned short* __restrict__ sgl, const unsigned short* __restrict__ wcat,
    const float* __restrict__ bcat, float* __restrict__ qp2,
    const float* __restrict__ pair, const unsigned short* __restrict__ wpbt,
    const float* __restrict__ bpb, unsigned short* __restrict__ pb,
    const unsigned short* __restrict__ wpoA, unsigned short* __restrict__ WB,
    const float* __restrict__ bpo, const float* __restrict__ Wo,
    const float* __restrict__ bo, float* __restrict__ bfused)
{
  __shared__ unsigned short shmem[8704];   // gemm: As(4096)+Bs(4096); pairbias: 8x1088
  const int bid = blockIdx.x;
  const int t = threadIdx.x;

  if (bid < 12) {             // wfuse: Wfused = Wpo @ Wo -> WB[:,768:912]
    int mb = bid & 1, nb = bid >> 1;
    gemm_dev<1>(shmem, shmem + 4096, wpoA, 768, 144, WB, 912, 768, 0, 24, 768,
                nullptr, WB, 912, nullptr, mb, nb, 0);
    return;
  }
  if (bid < 15) {             // bfused[n] = bpo @ Wo + bo
    int n = (bid - 12) * 256 + t;
    float sacc = bo[n];
    for (int j = 0; j < 768; ++j) sacc += bpo[j] * Wo[(size_t)j * 768 + n];
    bfused[n] = sacc;
    return;
  }
  if (bid < 367) {            // proj, k-split 2
    int pbid = bid - 15;
    int zk = pbid / 176, rem = pbid % 176;
    int mb = rem & 7, nb = rem >> 3;
    gemm_dev<0>(shmem, shmem + 4096, sgl, 768, 1024, wcat, 768, 2736,
                zk * 12, 12, 768,
                qp2 + (size_t)zk * QPSLAB, nullptr, 2736, bcat, mb, nb, zk == 0);
    return;
  }
  // ---- pairbias ----
  {
    const int lane = t & 63, w = t >> 6;
    const int lr = lane & 15, g = lane >> 4;
    unsigned short* b0 = shmem + (w * 2 + 0) * 1088;   // 16 rows x 68 ushorts
    unsigned short* b1 = shmem + (w * 2 + 1) * 1088;
    bf16x8 wf0 = *(const bf16x8*)(wpbt + lr * 64 + g * 8);
    bf16x8 wf1 = *(const bf16x8*)(wpbt + lr * 64 + 32 + g * 8);
    const float bias_h = (lr < 12) ? bpb[lr] : 0.f;
    const int wid = (bid - 367) * 4 + w;
    const float* base = pair + (size_t)wid * 4096;     // 4 tiles x 1024 floats

    // pack lane's float4 (row i*4+g, cols lr*4..+3) into buf
#define PB_WR(BUF, I, V)                                                         \
    do {                                                                         \
      union { __hip_bfloat162 h2[2]; ushort4 s4; } u_;                           \
      u_.h2[0] = __float22bfloat162_rn(make_float2((V).x, (V).y));               \
      u_.h2[1] = __float22bfloat162_rn(make_float2((V).z, (V).w));               \
      *(ushort4*)((BUF) + ((I) * 4 + g) * 68 + lr * 4) = u_.s4;                  \
    } while (0)

    {
      float4 v0 = *(const float4*)(base + 0 * 256 + lane * 4);
      float4 v1 = *(const float4*)(base + 1 * 256 + lane * 4);
      float4 v2 = *(const float4*)(base + 2 * 256 + lane * 4);
      float4 v3 = *(const float4*)(base + 3 * 256 + lane * 4);
      PB_WR(b0, 0, v0); PB_WR(b0, 1, v1); PB_WR(b0, 2, v2); PB_WR(b0, 3, v3);
    }
#pragma unroll
    for (int it = 0; it < 4; ++it) {
      unsigned short* cur = (it & 1) ? b1 : b0;
      unsigned short* nxt = (it & 1) ? b0 : b1;
      float4 n0, n1, n2, n3;
      if (it < 3) {
        const float* p = base + (it + 1) * 1024;
        n0 = *(const float4*)(p + 0 * 256 + lane * 4);
        n1 = *(const float4*)(p + 1 * 256 + lane * 4);
        n2 = *(const float4*)(p + 2 * 256 + lane * 4);
        n3 = *(const float4*)(p + 3 * 256 + lane * 4);
      }
      __syncthreads();
      union { ushort4 q[2]; bf16x8 v; } F0, F1;
      F0.q[0] = *(const ushort4*)(cur + lr * 68 + g * 8);
      F0.q[1] = *(const ushort4*)(cur + lr * 68 + g * 8 + 4);
      F1.q[0] = *(const ushort4*)(cur + lr * 68 + 32 + g * 8);
      F1.q[1] = *(const ushort4*)(cur + lr * 68 + 32 + g * 8 + 4);
      if (it < 3) { PB_WR(nxt, 0, n0); PB_WR(nxt, 1, n1);
                    PB_WR(nxt, 2, n2); PB_WR(nxt, 3, n3); }
      f32x4 c = {0.f, 0.f, 0.f, 0.f};
      c = __builtin_amdgcn_mfma_f32_16x16x32_bf16(F0.v, wf0, c, 0, 0, 0);
      c = __builtin_amdgcn_mfma_f32_16x16x32_bf16(F1.v, wf1, c, 0, 0, 0);
      if (lr < 12) {
        int nm0 = (wid * 4 + it) * 16;
        union { __hip_bfloat162 h2[2]; ushort4 s4; } pu;
        pu.h2[0] = __float22bfloat162_rn(make_float2(c[0] + bias_h, c[1] + bias_h));
        pu.h2[1] = __float22bfloat162_rn(make_float2(c[2] + bias_h, c[3] + bias_h));
        *(ushort4*)(pb + ((size_t)lr << 20) + (size_t)nm0 + g * 4) = pu.s4;
      }
    }
#undef PB_WR
  }
}

// ---------------------------------------------------------------------------
// rotate
// ---------------------------------------------------------------------------
__global__ __launch_bounds__(256) void rotate_k(
    const float* __restrict__ qp2, const float* __restrict__ rot,
    const float* __restrict__ trans,
    unsigned short* __restrict__ Acat, unsigned short* __restrict__ Bcat,
    unsigned short* __restrict__ VcatT, float* __restrict__ q2k2)
{
  const int n = blockIdx.x, t = threadIdx.x;
  __shared__ float R[9], T[3], rg[432];
  if (t < 9) R[t] = rot[n * 9 + t];
  if (t >= 9 && t < 12) T[t - 9] = trans[n * 3 + (t - 9)];
  __syncthreads();
  for (int s = t; s < 432; s += 256) {
    int j = s / 144, r = s % 144;
    int h = r / 12, wo = r % 12;
    int e = wo % 3;
    size_t base = (size_t)n * 2736 + 2304 + j * 144 + (r - e);
    float d0 = qp2[base + 0] + qp2[base + 0 + QPSLAB];
    float d1 = qp2[base + 1] + qp2[base + 1 + QPSLAB];
    float d2 = qp2[base + 2] + qp2[base + 2 + QPSLAB];
    float val = d0 * R[e] + d1 * R[3 + e] + d2 * R[6 + e] + T[e];
    rg[s] = val;
    unsigned short bv = f2bf(val);
    if (j == 0)      Acat[((size_t)h * NTOK + n) * 96 + 64 + wo] = bv;
    else if (j == 1) Bcat[((size_t)h * NTOK + n) * 96 + 64 + wo] = bv;
    else             VcatT[((size_t)h * 80 + 64 + wo) * NTOK + n] = bv;
  }
  __syncthreads();
  for (int s = t; s < 2304; s += 256) {
    int j = s / 768, c = s % 768;
    int h = c >> 6, cc = c & 63;
    size_t ix = (size_t)n * 2736 + s;
    unsigned short bv = f2bf(qp2[ix] + qp2[ix + QPSLAB]);
    if (j == 0)      Acat[((size_t)h * NTOK + n) * 96 + cc] = bv;
    else if (j == 1) Bcat[((size_t)h * NTOK + n) * 96 + cc] = bv;
    else             VcatT[((size_t)h * 80 + cc) * NTOK + n] = bv;
  }
  if (t < 240) {
    int h = t / 20, ix = 76 + t % 20;
    Acat[((size_t)h * NTOK + n) * 96 + ix] = 0;
    Bcat[((size_t)h * NTOK + n) * 96 + ix] = 0;
  }
  if (t >= 240 && t < 288) {
    int s = t - 240;
    int h = s / 4, rr = 76 + s % 4;
    VcatT[((size_t)h * 80 + rr) * NTOK + n] = 0;
  }
  if (t < 24) {
    int j = t / 12, h = t % 12;
    float sum = 0.f;
#pragma unroll
    for (int wo = 0; wo < 12; ++wo) {
      float v = rg[j * 144 + h * 12 + wo];
      sum += v * v;
    }
    q2k2[(size_t)(j * NH + h) * NTOK + n] = sum;
  }
}

// ---------------------------------------------------------------------------
// fused attention
// ---------------------------------------------------------------------------
__global__ __launch_bounds__(256) void attn_k(
    const unsigned short* __restrict__ pb, const unsigned short* __restrict__ Acat,
    const unsigned short* __restrict__ Bcat, const unsigned short* __restrict__ VcatT,
    const float* __restrict__ q2k2, float* __restrict__ acc4)
{
  __shared__ unsigned short Ls[64 * 256];
  __shared__ unsigned short Bs[128 * 104];
  const int t = threadIdx.x, w = t >> 6, lane = t & 63;
  const int lr = lane & 15, lc = lane >> 4;
  const int n0 = blockIdx.x * 64;
  const int m0 = blockIdx.y * 256;
  const int h  = blockIdx.z;

  const unsigned short* Pg = pb + ((size_t)h << 20) + (size_t)n0 * 1024 + m0;
#pragma unroll
  for (int i = 0; i < 8; ++i) {
    int idx = i * 256 + t;
    int row = idx >> 5, sl = idx & 31;
    u32x4 v = *(const u32x4*)(Pg + (size_t)row * 1024 + sl * 8);
    ((u32x4*)Ls)[row * 32 + (sl ^ (row & 7))] = v;
  }
  const unsigned short* Kg = Bcat + ((size_t)h * 1024 + m0) * 96;
#pragma unroll
  for (int i = 0; i < 6; ++i) {
    int idx = i * 256 + t;
    int row = idx / 12, c = idx % 12;
    u32x4 v = *(const u32x4*)(Kg + (size_t)row * 96 + c * 8);
    *(u32x4*)(Bs + row * 104 + c * 8) = v;
  }
  __syncthreads();

  bf16x8 qf[3];
  const unsigned short* Qg = Acat + ((size_t)h * 1024 + n0 + w * 16 + lr) * 96;
#pragma unroll
  for (int kk = 0; kk < 3; ++kk) qf[kk] = *(const bf16x8*)(Qg + kk * 32 + lc * 8);

  f32x4 sa[16];
#pragma unroll
  for (int ct = 0; ct < 16; ++ct) sa[ct] = (f32x4){0.f, 0.f, 0.f, 0.f};

#pragma unroll
  for (int ct = 0; ct < 8; ++ct)
#pragma unroll
    for (int kk = 0; kk < 3; ++kk) {
      bf16x8 kf = *(const bf16x8*)(Bs + (ct * 16 + lr) * 104 + kk * 32 + lc * 8);
      sa[ct] = __builtin_amdgcn_mfma_f32_16x16x32_bf16(kf, qf[kk], sa[ct], 0, 0, 0);
    }
  __syncthreads();
#pragma unroll
  for (int i = 0; i < 6; ++i) {
    int idx = i * 256 + t;
    int row = idx / 12, c = idx % 12;
    u32x4 v = *(const u32x4*)(Kg + (size_t)(128 + row) * 96 + c * 8);
    *(u32x4*)(Bs + row * 104 + c * 8) = v;
  }
  __syncthreads();
#pragma unroll
  for (int ct = 8; ct < 16; ++ct)
#pragma unroll
    for (int kk = 0; kk < 3; ++kk) {
      bf16x8 kf = *(const bf16x8*)(Bs + ((ct - 8) * 16 + lr) * 104 + kk * 32 + lc * 8);
      sa[ct] = __builtin_amdgcn_mfma_f32_16x16x32_bf16(kf, qf[kk], sa[ct], 0, 0, 0);
    }

  const int nrow = w * 16 + lr;
  const float q2v = q2k2[(size_t)h * 1024 + n0 + nrow];
  const float* k2b = q2k2 + 12288 + (size_t)h * 1024 + m0;
  float mx = -1e30f;
#pragma unroll
  for (int ct = 0; ct < 16; ++ct) {
    int sl = (ct * 2 + (lc >> 1)) ^ (nrow & 7);
    const unsigned short* p = Ls + nrow * 256 + sl * 8 + (lc & 1) * 4;
    ushort4 pv = *(const ushort4*)p;
    float4 k2v = *(const float4*)(k2b + ct * 16 + lc * 4);
    sa[ct][0] = 0.125f * sa[ct][0] + bf2f(pv.x) - 0.0625f * (q2v + k2v.x);
    sa[ct][1] = 0.125f * sa[ct][1] + bf2f(pv.y) - 0.0625f * (q2v + k2v.y);
    sa[ct][2] = 0.125f * sa[ct][2] + bf2f(pv.z) - 0.0625f * (q2v + k2v.z);
    sa[ct][3] = 0.125f * sa[ct][3] + bf2f(pv.w) - 0.0625f * (q2v + k2v.w);
    mx = fmaxf(mx, fmaxf(fmaxf(sa[ct][0], sa[ct][1]), fmaxf(sa[ct][2], sa[ct][3])));
  }
  mx = fmaxf(mx, __shfl_xor(mx, 16, 64));
  mx = fmaxf(mx, __shfl_xor(mx, 32, 64));
  float sm = 0.f;
#pragma unroll
  for (int ct = 0; ct < 16; ++ct)
#pragma unroll
    for (int r = 0; r < 4; ++r) { sa[ct][r] = __expf(sa[ct][r] - mx); sm += sa[ct][r]; }
  sm += __shfl_xor(sm, 16, 64);
  sm += __shfl_xor(sm, 32, 64);
  float inv = 1.0f / sm;
#pragma unroll
  for (int ct = 0; ct < 16; ++ct) {
    int sl = (ct * 2 + (lc >> 1)) ^ (nrow & 7);
    unsigned short* p = Ls + nrow * 256 + sl * 8 + (lc & 1) * 4;
    union { __hip_bfloat162 h2[2]; ushort4 s4; } pu;
    pu.h2[0] = __float22bfloat162_rn(make_float2(sa[ct][0] * inv, sa[ct][1] * inv));
    pu.h2[1] = __float22bfloat162_rn(make_float2(sa[ct][2] * inv, sa[ct][3] * inv));
    *(ushort4*)p = pu.s4;
  }
  __syncthreads();

  f32x4 acc[5];
#pragma unroll
  for (int nf = 0; nf < 5; ++nf) acc[nf] = (f32x4){0.f, 0.f, 0.f, 0.f};
  const unsigned short* Vg = VcatT + (size_t)h * 80 * NTOK + m0;
#pragma unroll
  for (int kk = 0; kk < 8; ++kk) {
    int row = w * 16 + lr;
    int sl = (kk * 4 + lc) ^ (row & 7);
    bf16x8 a = *(const bf16x8*)(Ls + row * 256 + sl * 8);
#pragma unroll
    for (int nf = 0; nf < 5; ++nf) {
      int c = nf * 16 + lr;
      bf16x8 b = *(const bf16x8*)(Vg + (size_t)c * NTOK + kk * 32 + lc * 8);
      acc[nf] = __builtin_amdgcn_mfma_f32_16x16x32_bf16(a, b, acc[nf], 0, 0, 0);
    }
  }
  float* out = acc4 + ((size_t)blockIdx.y * NH + h) * (size_t)NTOK * 80;
#pragma unroll
  for (int nf = 0; nf < 5; ++nf)
#pragma unroll
    for (int r = 0; r < 4; ++r) {
      int orow = n0 + w * 16 + lc * 4 + r;
      int c = nf * 16 + lr;
      out[(size_t)orow * 80 + c] = acc[nf][r];
    }
}

// ---------------------------------------------------------------------------
// reduce 4 chunk slabs -> AW bf16 [1024][912] = [ws | wp]
// ---------------------------------------------------------------------------
__global__ __launch_bounds__(256) void reduce_k(
    const float* __restrict__ acc4, unsigned short* __restrict__ AW)
{
  int idx = blockIdx.x * 256 + threadIdx.x;
  if (idx >= 1024 * 912) return;
  int n = idx / 912, c = idx % 912;
  const size_t cs = (size_t)NH * NTOK * 80;
  size_t base;
  if (c < 768) {
    int h = c >> 6, cc = c & 63;
    base = ((size_t)h * NTOK + n) * 80 + cc;
  } else {
    int c2 = c - 768;
    int h = c2 / 12, wo = c2 % 12;
    base = ((size_t)h * NTOK + n) * 80 + 64 + wo;
  }
  float v = acc4[base] + acc4[base + cs] + acc4[base + 2 * cs] + acc4[base + 3 * cs];
  AW[(size_t)n * 912 + c] = f2bf(v);
}

// ---------------------------------------------------------------------------
// tail gemm (k-split 4): outpre[z] = AW @ WB^T
// ---------------------------------------------------------------------------
__global__ __launch_bounds__(256) void tail_gemm_k(
    const unsigned short* __restrict__ AW, const unsigned short* __restrict__ WB,
    float* __restrict__ outpre)
{
  __shared__ unsigned short As[128 * 32];
  __shared__ unsigned short Bs[128 * 32];
  int z = blockIdx.z;
  int kt0 = z * 8, ktn = (z < 3) ? 8 : 5;
  gemm_dev<0>(As, Bs, AW, 912, 1024, WB, 912, 768, kt0, ktn, 912,
              outpre + (size_t)z * 786432, nullptr, 768, nullptr,
              blockIdx.x, blockIdx.y, 0);
}

// ---------------------------------------------------------------------------
// layernorm(single + sum(4 outpre slabs) + bfused) -> d_out
// ---------------------------------------------------------------------------
__global__ __launch_bounds__(256) void ln_k(
    const float* __restrict__ single, const float* __restrict__ outpre,
    const float* __restrict__ bfused, const float* __restrict__ g,
    const float* __restrict__ b, float* __restrict__ out)
{
  const int row = blockIdx.x, t = threadIdx.x;
  __shared__ float red[8];
  size_t base = (size_t)row * 768;
  const size_t SL = 786432;
  float x[3];
#pragma unroll
  for (int j = 0; j < 3; ++j) {
    int c = t + j * 256;
    float v = single[base + c] + bfused[c];
#pragma unroll
    for (int z = 0; z < 4; ++z) v += outpre[base + c + (size_t)z * SL];
    x[j] = v;
  }
  float s = x[0] + x[1] + x[2];
#pragma unroll
  for (int off = 32; off; off >>= 1) s += __shfl_xor(s, off, 64);
  if ((t & 63) == 0) red[t >> 6] = s;
  __syncthreads();
  float mu = (red[0] + red[1] + red[2] + red[3]) * (1.0f / 768.0f);
  float d0 = x[0] - mu, d1 = x[1] - mu, d2 = x[2] - mu;
  float vs = d0 * d0 + d1 * d1 + d2 * d2;
#pragma unroll
  for (int off = 32; off; off >>= 1) vs += __shfl_xor(vs, off, 64);
  if ((t & 63) == 0) red[4 + (t >> 6)] = vs;
  __syncthreads();
  float var = (red[4] + red[5] + red[6] + red[7]) * (1.0f / 768.0f);
  float rs = rsqrtf(var + 1e-5f);
  out[base + t]       = d0 * rs * g[t]       + b[t];
  out[base + t + 256] = d1 * rs * g[t + 256] + b[t + 256];
  out[base + t + 512] = d2 * rs * g[t + 512] + b[t + 512];
}

// ---------------------------------------------------------------------------
extern "C" void kernel_launch(void* const* d_in, const int* in_sizes, int n_in,
                              void* d_out, int out_size, void* d_ws, size_t ws_size,
                              hipStream_t stream)
{
  (void)in_sizes; (void)n_in; (void)out_size; (void)ws_size;
  const float* single = (const float*)d_in[0];
  const float* pair   = (const float*)d_in[1];
  const float* rot    = (const float*)d_in[2];
  const float* trans  = (const float*)d_in[3];
  const float* Wq  = (const float*)d_in[4];  const float* bq  = (const float*)d_in[5];
  const float* Wk  = (const float*)d_in[6];  const float* bk  = (const float*)d_in[7];
  const float* Wv  = (const float*)d_in[8];  const float* bv  = (const float*)d_in[9];
  const float* Wpb = (const float*)d_in[10]; const float* bpb = (const float*)d_in[11];
  const float* Wqp = (const float*)d_in[12]; const float* bqp = (const float*)d_in[13];
  const float* Wkp = (const float*)d_in[14]; const float* bkp = (const float*)d_in[15];
  const float* Wvp = (const float*)d_in[16]; const float* bvp = (const float*)d_in[17];
  const float* Wo  = (const float*)d_in[18]; const float* bo  = (const float*)d_in[19];
  const float* Wpo = (const float*)d_in[20]; const float* bpo = (const float*)d_in[21];
  const float* lng = (const float*)d_in[22]; const float* lnb = (const float*)d_in[23];

  char* ws = (char*)d_ws;
  unsigned short* sgl    = (unsigned short*)(ws + 0);
  unsigned short* wcat   = (unsigned short*)(ws + 1572864);
  unsigned short* wpoA   = (unsigned short*)(ws + 5775360);
  unsigned short* WB     = (unsigned short*)(ws + 5996544);
  float*          bcat   = (float*)(ws + 7397376);
  unsigned short* wpbt   = (unsigned short*)(ws + 7408320);
  float*          bfused = (float*)(ws + 7410432);
  float*          qp2    = (float*)(ws + 7413504);
  unsigned short* Acat   = (unsigned short*)(ws + 29826816);
  unsigned short* Bcat   = (unsigned short*)(ws + 32186112);
  unsigned short* VcatT  = (unsigned short*)(ws + 34545408);
  float*          q2k2   = (float*)(ws + 36511488);
  unsigned short* pb     = (unsigned short*)(ws + 36609792);
  float*          acc4   = (float*)(ws + 61775616);   // [4][12*1024*80] f32
  unsigned short* AW     = (unsigned short*)(ws + 77504256);
  float*          outpre = (float*)(ws + 79372032);   // [4][1024][768] f32

  prep_k<<<3519, 256, 0, stream>>>(single, Wq, Wk, Wv, Wqp, Wkp, Wvp, Wpo, Wo,
                                   Wpb, bq, bk, bv, bqp, bkp, bvp,
                                   sgl, wcat, WB, wpoA, bcat, wpbt);

  fat_k<<<4463, 256, 0, stream>>>(sgl, wcat, bcat, qp2, pair, wpbt, bpb, pb,
                                  wpoA, WB, bpo, Wo, bo, bfused);

  rotate_k<<<1024, 256, 0, stream>>>(qp2, rot, trans, Acat, Bcat, VcatT, q2k2);

  attn_k<<<dim3(16, 4, 12), 256, 0, stream>>>(pb, Acat, Bcat, VcatT, q2k2, acc4);

  reduce_k<<<3648, 256, 0, stream>>>(acc4, AW);

  tail_gemm_k<<<dim3(8, 6, 4), 256, 0, stream>>>(AW, WB, outpre);

  ln_k<<<1024, 256, 0, stream>>>(single, outpre, bfused, lng, lnb, (float*)d_out);
}